// Round 8
// baseline (384.520 us; speedup 1.0000x reference)
//
#include <hip/hip_runtime.h>
#include <hip/hip_bf16.h>

// FullyConnectedTensorProduct: irreps 64x(0e+1o+2e) x same -> same, N=4096.
// out[z, OFF[io] + w*(2lo+1) + k] = (1/24) * sum_p sum_{u,v,i,j} W[p][u][v][w]*CG_p[i,j,k]*x1[z,u,i]*x2[z,v,j]
//
// R8 = R7 (kout-merged units, ZT=64, u-split US=4, partials+reduce, cvt_pk pack)
// + chunk=2u (16 KiB, dbuf 32 KiB) + __launch_bounds__(256,3) -> 3 blocks/CU, 12 waves/CU
// + a1 prefetched one chunk ahead and issued BEFORE the stage (kills the per-chunk
//   vmcnt(0) drain that exposed staging latency in R6/R7).

typedef unsigned short u16;
typedef __attribute__((ext_vector_type(8))) short bf16x8;   // 8 bf16 in 4 VGPRs
typedef __attribute__((ext_vector_type(4))) float f32x4;

#define NZ 4096
#define ROWE 832   // padded bf16 elems per z-row: seg0 64*1 + seg1 64*4 + seg2 64*8

__device__ __forceinline__ u16 f2bf(float x) {               // RNE f32->bf16 (prep only)
    unsigned u = __float_as_uint(x);
    return (u16)((u + 0x7FFFu + ((u >> 16) & 1u)) >> 16);
}
__device__ __forceinline__ float bf2f(u16 b) {
    return __uint_as_float(((unsigned)b) << 16);
}

// ---------------- Clebsch-Gordan tables (real basis, reference phase conventions) ----
struct CGE { int i, j, k; float c; };
template<int P> struct CGT;
template<> struct CGT<0> { static constexpr int n=1; static constexpr CGE e[1]={{0,0,0,1.0f}}; };
template<> struct CGT<1> { static constexpr int n=3; static constexpr CGE e[3]={
    {0,0,0,0.5773502691896258f},{1,1,0,0.5773502691896258f},{2,2,0,0.5773502691896258f}}; };
template<> struct CGT<2> { static constexpr int n=5; static constexpr CGE e[5]={
    {0,0,0,0.4472135954999579f},{1,1,0,0.4472135954999579f},{2,2,0,0.4472135954999579f},
    {3,3,0,0.4472135954999579f},{4,4,0,0.4472135954999579f}}; };
template<> struct CGT<3> { static constexpr int n=3; static constexpr CGE e[3]={
    {0,0,0,1.0f},{0,1,1,1.0f},{0,2,2,1.0f}}; };
template<> struct CGT<4> { static constexpr int n=3; static constexpr CGE e[3]={
    {0,0,0,1.0f},{1,0,1,1.0f},{2,0,2,1.0f}}; };
template<> struct CGT<5> { static constexpr int n=11; static constexpr CGE e[11]={
    {0,2,0,-0.31622776601683794f},{1,1,0,0.5477225575051661f},{0,4,0,-0.5477225575051661f},{2,0,0,0.5477225575051661f},
    {0,1,1,0.5477225575051661f},{2,3,1,0.5477225575051661f},{1,2,1,0.6324555320336759f},
    {2,2,2,-0.31622776601683794f},{1,3,2,0.5477225575051661f},{0,0,2,0.5477225575051661f},{2,4,2,0.5477225575051661f}}; };
template<> struct CGT<6> { static constexpr int n=11; static constexpr CGE e[11]={
    {2,0,0,-0.31622776601683794f},{1,1,0,0.5477225575051661f},{4,0,0,-0.5477225575051661f},{0,2,0,0.5477225575051661f},
    {1,0,1,0.5477225575051661f},{3,2,1,0.5477225575051661f},{2,1,1,0.6324555320336759f},
    {2,2,2,-0.31622776601683794f},{3,1,2,0.5477225575051661f},{0,0,2,0.5477225575051661f},{4,2,2,0.5477225575051661f}}; };
template<> struct CGT<7> { static constexpr int n=5; static constexpr CGE e[5]={
    {0,0,0,1.0f},{0,1,1,1.0f},{0,2,2,1.0f},{0,3,3,1.0f},{0,4,4,1.0f}}; };
template<> struct CGT<8> { static constexpr int n=11; static constexpr CGE e[11]={
    {0,2,0,0.7071067811865476f},{2,0,0,0.7071067811865476f},
    {0,1,1,0.7071067811865476f},{1,0,1,0.7071067811865476f},
    {0,0,2,-0.4082482904638630f},{1,1,2,0.8164965809277260f},{2,2,2,-0.4082482904638630f},
    {1,2,3,0.7071067811865476f},{2,1,3,0.7071067811865476f},
    {0,0,4,-0.7071067811865476f},{2,2,4,0.7071067811865476f}}; };
template<> struct CGT<9> { static constexpr int n=5; static constexpr CGE e[5]={
    {0,0,0,1.0f},{1,0,1,1.0f},{2,0,2,1.0f},{3,0,3,1.0f},{4,0,4,1.0f}}; };
template<> struct CGT<10> { static constexpr int n=25; static constexpr CGE e[25]={
    {0,2,0,-0.5345224838248488f},{2,0,0,-0.5345224838248488f},{1,3,0,0.4629100498862757f},{3,1,0,0.4629100498862757f},
    {0,3,1,0.4629100498862757f},{3,0,1,0.4629100498862757f},{1,4,1,-0.4629100498862757f},{4,1,1,-0.4629100498862757f},
    {1,2,1,0.2672612419124244f},{2,1,1,0.2672612419124244f},
    {0,0,2,-0.5345224838248488f},{1,1,2,0.2672612419124244f},{2,2,2,0.5345224838248488f},{3,3,2,0.2672612419124244f},{4,4,2,-0.5345224838248488f},
    {0,1,3,0.4629100498862757f},{1,0,3,0.4629100498862757f},{3,4,3,0.4629100498862757f},{4,3,3,0.4629100498862757f},
    {2,3,3,0.2672612419124244f},{3,2,3,0.2672612419124244f},
    {1,1,4,-0.4629100498862757f},{3,3,4,0.4629100498862757f},{2,4,4,-0.5345224838248488f},{4,2,4,-0.5345224838248488f}}; };

// ---------------- padded x layout helpers ----------------
template<int SEG>
__device__ __forceinline__ int soff(int m) {
    if constexpr (SEG == 0) return m;              // width 1
    else if constexpr (SEG == 1) return 64 + 4*m;  // width 3 padded to 4
    else return 320 + 8*m;                         // width 5 padded to 8
}
template<int L>
__device__ __forceinline__ void load_xvec(const u16* p, float* o) {
    if constexpr (L == 0) {
        o[0] = bf2f(p[0]);
    } else if constexpr (L == 1) {
        uint2 r = *reinterpret_cast<const uint2*>(p);
        o[0] = bf2f((u16)(r.x & 0xffff)); o[1] = bf2f((u16)(r.x >> 16)); o[2] = bf2f((u16)(r.y & 0xffff));
    } else {
        uint4 r = *reinterpret_cast<const uint4*>(p);
        o[0] = bf2f((u16)(r.x & 0xffff)); o[1] = bf2f((u16)(r.x >> 16));
        o[2] = bf2f((u16)(r.y & 0xffff)); o[3] = bf2f((u16)(r.y >> 16));
        o[4] = bf2f((u16)(r.z & 0xffff));
    }
}

// ---------------- LDS staging: one chunk = 2 consecutive u = 16 KiB -----------------
// Wt layout: chunk g = pid*32 + (u>>1); 16B unit (w, m=(u&1)*8+h*4+kb) at slot
// w*16 + (m ^ (w&15)). Bank-balanced on ds_read_b128 (8 lanes per 4-bank group).
__device__ __forceinline__ void stage_chunk(const u16* __restrict__ Wtb, int g,
                                            u16* lbuf, int tid) {
    const u16* src = Wtb + ((size_t)g << 13);
    #pragma unroll
    for (int qq = 0; qq < 4; ++qq) {
        const int off = qq*2048 + tid*8;       // 16B per thread, lane-linear
        __builtin_amdgcn_global_load_lds(
            (const __attribute__((address_space(1))) void*)(const void*)(src + off),
            (__attribute__((address_space(3))) void*)(void*)(lbuf + off),
            16, 0, 0);
    }
}

// ---------------- one chunk (2 u), consumed by every z-wave; KO kouts share B-frags -
template<int PID, int S1, int S2, int KO>
__device__ __forceinline__ void chunk_compute(const u16* __restrict__ lbuf,
                                              const float (&a1)[2][2*S1+1],
                                              const float (&b2)[16][2*S2+1],
                                              f32x4 (&acc)[KO][4], int lane) {
    const int kb = lane >> 4, nl = lane & 15;
    #pragma unroll
    for (int uu = 0; uu < 2; ++uu) {
        float pre[CGT<PID>::n];
        #pragma unroll
        for (int t = 0; t < CGT<PID>::n; ++t)
            pre[t] = CGT<PID>::e[t].c * a1[uu][CGT<PID>::e[t].i];
        #pragma unroll
        for (int h = 0; h < 2; ++h) {
            bf16x8 bf[4];
            #pragma unroll
            for (int nf = 0; nf < 4; ++nf) {
                const int w = nf*16 + nl;
                const int slot = w*16 + ((uu*8 + h*4 + kb) ^ (w & 15));
                bf[nf] = *reinterpret_cast<const bf16x8*>(lbuf + slot*8);
            }
            #pragma unroll
            for (int ko = 0; ko < KO; ++ko) {
                union { unsigned u[4]; bf16x8 v; } af;
                #pragma unroll
                for (int qq = 0; qq < 4; ++qq) {       // pairwise: short s-liveness
                    float s0 = 0.f, s1 = 0.f;
                    #pragma unroll
                    for (int t = 0; t < CGT<PID>::n; ++t)
                        if (CGT<PID>::e[t].k == ko) {
                            s0 += pre[t] * b2[h*8 + 2*qq    ][CGT<PID>::e[t].j];
                            s1 += pre[t] * b2[h*8 + 2*qq + 1][CGT<PID>::e[t].j];
                        }
                    __hip_bfloat162 t2 = __float22bfloat162_rn(make_float2(s0, s1));
                    unsigned r; __builtin_memcpy(&r, &t2, 4);
                    af.u[qq] = r;
                }
                #pragma unroll
                for (int nf = 0; nf < 4; ++nf)
                    acc[ko][nf] = __builtin_amdgcn_mfma_f32_16x16x32_bf16(af.v, bf[nf], acc[ko][nf], 0, 0, 0);
            }
        }
    }
}

// ---------------- one path: CPP chunks (u = uq*CPP*2 + c*2 + uu), dbuf staging ------
// Ordering per chunk: barrier -> a1n prefetch (BEFORE stage) -> stage q+1 -> compute q.
// All global loads used by compute were issued before the barrier -> no mid-compute
// vmcnt drain; stage q+1 has a full chunk-compute to land before the next barrier.
template<int PID, int S1, int S2, int KO, int CPP>
__device__ __forceinline__ void run_path(const u16* __restrict__ x1r, const u16* __restrict__ x2r,
                                         const u16* __restrict__ Wtb, u16* lds,
                                         f32x4 (&acc)[KO][4], int lane, int tid, int uq,
                                         int& q, int nq, int GB) {
    constexpr int D1 = 2*S1 + 1, D2 = 2*S2 + 1;
    const int kb = lane >> 4;
    float b2[16][D2];
    #pragma unroll
    for (int h = 0; h < 2; ++h)
        #pragma unroll
        for (int e = 0; e < 8; ++e)
            load_xvec<S2>(x2r + soff<S2>(h*32 + kb*8 + e), b2[h*8 + e]);

    const int ubase = uq*(CPP*2);
    float a1[2][D1], a1n[2][D1];
    #pragma unroll
    for (int uu = 0; uu < 2; ++uu)
        load_xvec<S1>(x1r + soff<S1>(ubase + uu), a1[uu]);

    for (int c = 0; c < CPP; ++c) {
        __syncthreads();                          // chunk q staged; all readers past q^1
        const int cn = (c + 1) & (CPP - 1);       // prefetch next chunk's a1 FIRST
        #pragma unroll
        for (int uu = 0; uu < 2; ++uu)
            load_xvec<S1>(x1r + soff<S1>(ubase + cn*2 + uu), a1n[uu]);
        if (q + 1 < nq) {
            const int qn = q + 1;
            const int g = GB + (qn/CPP)*32 + uq*CPP + (qn%CPP);   // CPP is pow2
            stage_chunk(Wtb, g, lds + ((qn & 1) << 13), tid);
        }
        chunk_compute<PID,S1,S2,KO>(lds + ((q & 1) << 13), a1, b2, acc, lane);
        #pragma unroll
        for (int uu = 0; uu < 2; ++uu)
            #pragma unroll
            for (int d = 0; d < D1; ++d) a1[uu][d] = a1n[uu][d];
        ++q;
    }
}

// ---------------- one unit = (ztile64, io, uq): partials or direct out --------------
template<int IO, int US>
__device__ __forceinline__ void run_unit(const u16* __restrict__ XB1, const u16* __restrict__ XB2,
                                         const u16* __restrict__ Wtb, float* __restrict__ dst,
                                         int zt, int uq, u16* lds) {
    constexpr int KO   = 2*IO + 1;
    constexpr int NP   = (IO == 0) ? 3 : 4;
    constexpr int GB   = (IO == 0) ? 0 : (IO == 1 ? 96 : 224);   // first pid * 32
    constexpr int OFFI = (IO == 0) ? 0 : (IO == 1 ? 64 : 256);
    constexpr int CPP  = 32/US;                   // chunks per path in this block
    const int tid = threadIdx.x;
    const int lane = tid & 63, wave = tid >> 6;   // wave = z-subtile
    const int zin = zt*64 + wave*16 + (lane & 15);
    const u16* x1r = XB1 + (size_t)zin*ROWE;
    const u16* x2r = XB2 + (size_t)zin*ROWE;
    f32x4 acc[KO][4];
    #pragma unroll
    for (int k = 0; k < KO; ++k)
        #pragma unroll
        for (int nf = 0; nf < 4; ++nf) acc[k][nf] = (f32x4){0.f, 0.f, 0.f, 0.f};

    int q = 0;
    stage_chunk(Wtb, GB + uq*CPP, lds, tid);      // prologue: chunk 0 -> buf 0

    if constexpr (IO == 0) {
        run_path<0,0,0,KO,CPP>(x1r, x2r, Wtb, lds, acc, lane, tid, uq, q, NP*CPP, GB);
        run_path<1,1,1,KO,CPP>(x1r, x2r, Wtb, lds, acc, lane, tid, uq, q, NP*CPP, GB);
        run_path<2,2,2,KO,CPP>(x1r, x2r, Wtb, lds, acc, lane, tid, uq, q, NP*CPP, GB);
    } else if constexpr (IO == 1) {
        run_path<3,0,1,KO,CPP>(x1r, x2r, Wtb, lds, acc, lane, tid, uq, q, NP*CPP, GB);
        run_path<4,1,0,KO,CPP>(x1r, x2r, Wtb, lds, acc, lane, tid, uq, q, NP*CPP, GB);
        run_path<5,1,2,KO,CPP>(x1r, x2r, Wtb, lds, acc, lane, tid, uq, q, NP*CPP, GB);
        run_path<6,2,1,KO,CPP>(x1r, x2r, Wtb, lds, acc, lane, tid, uq, q, NP*CPP, GB);
    } else {
        run_path<7,0,2,KO,CPP>(x1r, x2r, Wtb, lds, acc, lane, tid, uq, q, NP*CPP, GB);
        run_path<8,1,1,KO,CPP>(x1r, x2r, Wtb, lds, acc, lane, tid, uq, q, NP*CPP, GB);
        run_path<9,2,0,KO,CPP>(x1r, x2r, Wtb, lds, acc, lane, tid, uq, q, NP*CPP, GB);
        run_path<10,2,2,KO,CPP>(x1r, x2r, Wtb, lds, acc, lane, tid, uq, q, NP*CPP, GB);
    }

    // epilogue: C/D layout col=lane&15 (w), row=(lane>>4)*4+reg (z); no LDS reduction
    const int nl = lane & 15;
    const int zoutb = zt*64 + wave*16 + (lane >> 4)*4;
    #pragma unroll
    for (int k = 0; k < KO; ++k)
        #pragma unroll
        for (int nf = 0; nf < 4; ++nf) {
            const int wcol = nf*16 + nl;
            #pragma unroll
            for (int r = 0; r < 4; ++r) {
                const size_t idx = (size_t)(zoutb + r)*576 + OFFI + wcol*KO + k;
                if constexpr (US == 1) dst[idx] = acc[k][nf][r] * 0.041666666666666664f;
                else                   dst[idx] = acc[k][nf][r];
            }
        }
}

template<int US>
__global__ __launch_bounds__(256, 3) void tp_main(const u16* __restrict__ XB1, const u16* __restrict__ XB2,
                                                  const u16* __restrict__ Wtb, float* __restrict__ dst) {
    __shared__ u16 smem[2*8192];                  // 32 KiB, double-buffered 16 KiB chunks
    const int per = 3*US;
    const int zt  = blockIdx.x / per;
    const int rr  = blockIdx.x % per;
    const int io  = 2 - rr / US;                  // io2 (longest) dispatches first
    const int uq  = rr % US;
    float* dstP = (US == 1) ? dst : dst + (size_t)uq*NZ*576;
    if (io == 0)      run_unit<0,US>(XB1, XB2, Wtb, dstP, zt, uq, smem);
    else if (io == 1) run_unit<1,US>(XB1, XB2, Wtb, dstP, zt, uq, smem);
    else              run_unit<2,US>(XB1, XB2, Wtb, dstP, zt, uq, smem);
}

// ---------------- partial-sum reduction (deterministic, f32) ------------------------
template<int US>
__global__ __launch_bounds__(256) void reduce_k(const float* __restrict__ P, float* __restrict__ out) {
    const int i = blockIdx.x*256 + threadIdx.x;   // float4 index; grid sized exactly
    float4 s = reinterpret_cast<const float4*>(P)[i];
    #pragma unroll
    for (int u = 1; u < US; ++u) {
        float4 t = reinterpret_cast<const float4*>(P + (size_t)u*NZ*576)[i];
        s.x += t.x; s.y += t.y; s.z += t.z; s.w += t.w;
    }
    const float sc = 0.041666666666666664f;
    float4 o; o.x = s.x*sc; o.y = s.y*sc; o.z = s.z*sc; o.w = s.w*sc;
    reinterpret_cast<float4*>(out)[i] = o;
}

// ---------------- prep kernels ----------------
// x -> padded bf16 rows [z][ROWE]
__global__ void prep_x(const float* __restrict__ x1, const float* __restrict__ x2,
                       u16* __restrict__ XB1, u16* __restrict__ XB2) {
    int g = blockIdx.x * 256 + threadIdx.x;
    const int PER = NZ * 192;
    if (g >= 2*PER) return;
    const float* src; u16* dst;
    if (g < PER) { src = x1; dst = XB1; } else { src = x2; dst = XB2; g -= PER; }
    const int zz = g / 192, s = g - zz*192, seg = s >> 6, m = s & 63;
    const float* sp = src + zz*576;
    u16* dp = dst + zz*ROWE;
    if (seg == 0) {
        dp[m] = f2bf(sp[m]);
    } else if (seg == 1) {
        u16 t0 = f2bf(sp[64 + m*3 + 0]);
        u16 t1 = f2bf(sp[64 + m*3 + 1]);
        u16 t2 = f2bf(sp[64 + m*3 + 2]);
        uint2 pk; pk.x = (unsigned)t0 | ((unsigned)t1 << 16); pk.y = (unsigned)t2;
        *reinterpret_cast<uint2*>(dp + 64 + m*4) = pk;
    } else {
        u16 t[5];
        #pragma unroll
        for (int c = 0; c < 5; ++c) t[c] = f2bf(sp[256 + m*5 + c]);
        uint4 pk;
        pk.x = (unsigned)t[0] | ((unsigned)t[1] << 16);
        pk.y = (unsigned)t[2] | ((unsigned)t[3] << 16);
        pk.z = (unsigned)t[4];
        pk.w = 0u;
        *reinterpret_cast<uint4*>(dp + 320 + m*8) = pk;
    }
}

// W[p][u][v][w] f32 -> chunked/swizzled bf16 (16 KiB chunks):
// chunk g = p*32 + (u>>1); 16B unit (w, m=(u&1)*8 + h*4 + kb) at slot w*16 + (m^(w&15)),
// holding W[p][u][h*32+kb*8+e][w] for e=0..7.
__global__ void prep_w(const float* __restrict__ W, u16* __restrict__ Wtb) {
    __shared__ float ld[4096];
    const int b = blockIdx.x;            // 0..703 : (p,u)
    const int p = b >> 6, u = b & 63;
    const int tid = threadIdx.x;
    const float* src = W + ((size_t)(p*64 + u) << 12);
    #pragma unroll
    for (int i = 0; i < 16; ++i) ld[tid + i*256] = src[tid + i*256];   // coalesced
    __syncthreads();
    const int g  = p*32 + (u >> 1);
    const int mb = (u & 1)*8;
    #pragma unroll
    for (int r = 0; r < 2; ++r) {
        const int j = r*256 + tid;                 // 512 16B-units for this (p,u)
        const int w = j & 63, ms = j >> 6;         // ms = h*4+kb in [0,8)
        const int m = mb + ms;
        const int h = ms >> 2, kb = ms & 3;
        const int vb = h*32 + kb*8;
        u16 tmp[8];
        #pragma unroll
        for (int e = 0; e < 8; ++e) tmp[e] = f2bf(ld[(vb + e)*64 + w]);
        const int unit = w*16 + (m ^ (w & 15));
        uint4 pk;
        pk.x = (unsigned)tmp[0] | ((unsigned)tmp[1] << 16);
        pk.y = (unsigned)tmp[2] | ((unsigned)tmp[3] << 16);
        pk.z = (unsigned)tmp[4] | ((unsigned)tmp[5] << 16);
        pk.w = (unsigned)tmp[6] | ((unsigned)tmp[7] << 16);
        *reinterpret_cast<uint4*>(Wtb + (size_t)g*8192 + (size_t)unit*8) = pk;
    }
}

extern "C" void kernel_launch(void* const* d_in, const int* in_sizes, int n_in,
                              void* d_out, int out_size, void* d_ws, size_t ws_size,
                              hipStream_t stream) {
    const float* x1 = (const float*)d_in[0];
    const float* x2 = (const float*)d_in[1];
    const float* W  = (const float*)d_in[2];
    float* out = (float*)d_out;

    u16* XB1 = (u16*)d_ws;                 // 4096*832*2  = 6.8 MB
    u16* XB2 = XB1 + NZ*ROWE;              // 6.8 MB
    u16* Wtb = XB2 + NZ*ROWE;              // 11*32*8192*2 = 5.8 MB
    const size_t baseu = (size_t)2*NZ*ROWE + (size_t)11*32*8192;     // u16 elems
    if (ws_size < baseu*2) return;
    float* Pbuf = (float*)(XB1 + baseu);   // 16B-aligned (baseu*2 % 16 == 0)
    const size_t avail = ws_size - baseu*2;
    const size_t psz = (size_t)NZ*576*4;   // one partial slab, 9.4 MB
    const int US = (avail >= 4*psz) ? 4 : (avail >= 2*psz) ? 2 : 1;

    hipLaunchKernelGGL(prep_x, dim3((2*NZ*192 + 255)/256), dim3(256), 0, stream, x1, x2, XB1, XB2);
    hipLaunchKernelGGL(prep_w, dim3(11*64), dim3(256), 0, stream, W, Wtb);

    const int RED_GRID = NZ*576/4/256;     // 2304, exact
    if (US == 4) {
        hipLaunchKernelGGL(tp_main<4>, dim3(64*12), dim3(256), 0, stream, XB1, XB2, Wtb, Pbuf);
        hipLaunchKernelGGL(reduce_k<4>, dim3(RED_GRID), dim3(256), 0, stream, Pbuf, out);
    } else if (US == 2) {
        hipLaunchKernelGGL(tp_main<2>, dim3(64*6), dim3(256), 0, stream, XB1, XB2, Wtb, Pbuf);
        hipLaunchKernelGGL(reduce_k<2>, dim3(RED_GRID), dim3(256), 0, stream, Pbuf, out);
    } else {
        hipLaunchKernelGGL(tp_main<1>, dim3(64*3), dim3(256), 0, stream, XB1, XB2, Wtb, out);
    }
}

// Round 9
// 153.919 us; speedup vs baseline: 2.4982x; 2.4982x over previous
//
#include <hip/hip_runtime.h>
#include <hip/hip_bf16.h>

// FullyConnectedTensorProduct: irreps 64x(0e+1o+2e) x same -> same, N=4096.
// out[z, OFF[io] + w*(2lo+1) + k] = (1/24) * sum_p sum_{u,v,i,j} W[p][u][v][w]*CG_p[i,j,k]*x1[z,u,i]*x2[z,v,j]
//
// R9 = R7 resource shape (4u/32KiB chunks, dbuf 64 KiB LDS, no min-wave bound; R8's
// forced occupancy spilled: VGPR 84 + 484 MB scratch) + two safe fixes:
//  (a) a1 double-buffered one chunk ahead, loads issued BEFORE the stage issue so the
//      staging prefetch is never drained mid-loop (R7 drained it every chunk);
//  (b) pairwise af build (short s-liveness);
//  (c) unit-major grid decode (same-W blocks adjacent -> W slice L2-resident per XCD).

typedef unsigned short u16;
typedef __attribute__((ext_vector_type(8))) short bf16x8;   // 8 bf16 in 4 VGPRs
typedef __attribute__((ext_vector_type(4))) float f32x4;

#define NZ 4096
#define ROWE 832   // padded bf16 elems per z-row: seg0 64*1 + seg1 64*4 + seg2 64*8

__device__ __forceinline__ u16 f2bf(float x) {               // RNE f32->bf16 (prep only)
    unsigned u = __float_as_uint(x);
    return (u16)((u + 0x7FFFu + ((u >> 16) & 1u)) >> 16);
}
__device__ __forceinline__ float bf2f(u16 b) {
    return __uint_as_float(((unsigned)b) << 16);
}

// ---------------- Clebsch-Gordan tables (real basis, reference phase conventions) ----
struct CGE { int i, j, k; float c; };
template<int P> struct CGT;
template<> struct CGT<0> { static constexpr int n=1; static constexpr CGE e[1]={{0,0,0,1.0f}}; };
template<> struct CGT<1> { static constexpr int n=3; static constexpr CGE e[3]={
    {0,0,0,0.5773502691896258f},{1,1,0,0.5773502691896258f},{2,2,0,0.5773502691896258f}}; };
template<> struct CGT<2> { static constexpr int n=5; static constexpr CGE e[5]={
    {0,0,0,0.4472135954999579f},{1,1,0,0.4472135954999579f},{2,2,0,0.4472135954999579f},
    {3,3,0,0.4472135954999579f},{4,4,0,0.4472135954999579f}}; };
template<> struct CGT<3> { static constexpr int n=3; static constexpr CGE e[3]={
    {0,0,0,1.0f},{0,1,1,1.0f},{0,2,2,1.0f}}; };
template<> struct CGT<4> { static constexpr int n=3; static constexpr CGE e[3]={
    {0,0,0,1.0f},{1,0,1,1.0f},{2,0,2,1.0f}}; };
template<> struct CGT<5> { static constexpr int n=11; static constexpr CGE e[11]={
    {0,2,0,-0.31622776601683794f},{1,1,0,0.5477225575051661f},{0,4,0,-0.5477225575051661f},{2,0,0,0.5477225575051661f},
    {0,1,1,0.5477225575051661f},{2,3,1,0.5477225575051661f},{1,2,1,0.6324555320336759f},
    {2,2,2,-0.31622776601683794f},{1,3,2,0.5477225575051661f},{0,0,2,0.5477225575051661f},{2,4,2,0.5477225575051661f}}; };
template<> struct CGT<6> { static constexpr int n=11; static constexpr CGE e[11]={
    {2,0,0,-0.31622776601683794f},{1,1,0,0.5477225575051661f},{4,0,0,-0.5477225575051661f},{0,2,0,0.5477225575051661f},
    {1,0,1,0.5477225575051661f},{3,2,1,0.5477225575051661f},{2,1,1,0.6324555320336759f},
    {2,2,2,-0.31622776601683794f},{3,1,2,0.5477225575051661f},{0,0,2,0.5477225575051661f},{4,2,2,0.5477225575051661f}}; };
template<> struct CGT<7> { static constexpr int n=5; static constexpr CGE e[5]={
    {0,0,0,1.0f},{0,1,1,1.0f},{0,2,2,1.0f},{0,3,3,1.0f},{0,4,4,1.0f}}; };
template<> struct CGT<8> { static constexpr int n=11; static constexpr CGE e[11]={
    {0,2,0,0.7071067811865476f},{2,0,0,0.7071067811865476f},
    {0,1,1,0.7071067811865476f},{1,0,1,0.7071067811865476f},
    {0,0,2,-0.4082482904638630f},{1,1,2,0.8164965809277260f},{2,2,2,-0.4082482904638630f},
    {1,2,3,0.7071067811865476f},{2,1,3,0.7071067811865476f},
    {0,0,4,-0.7071067811865476f},{2,2,4,0.7071067811865476f}}; };
template<> struct CGT<9> { static constexpr int n=5; static constexpr CGE e[5]={
    {0,0,0,1.0f},{1,0,1,1.0f},{2,0,2,1.0f},{3,0,3,1.0f},{4,0,4,1.0f}}; };
template<> struct CGT<10> { static constexpr int n=25; static constexpr CGE e[25]={
    {0,2,0,-0.5345224838248488f},{2,0,0,-0.5345224838248488f},{1,3,0,0.4629100498862757f},{3,1,0,0.4629100498862757f},
    {0,3,1,0.4629100498862757f},{3,0,1,0.4629100498862757f},{1,4,1,-0.4629100498862757f},{4,1,1,-0.4629100498862757f},
    {1,2,1,0.2672612419124244f},{2,1,1,0.2672612419124244f},
    {0,0,2,-0.5345224838248488f},{1,1,2,0.2672612419124244f},{2,2,2,0.5345224838248488f},{3,3,2,0.2672612419124244f},{4,4,2,-0.5345224838248488f},
    {0,1,3,0.4629100498862757f},{1,0,3,0.4629100498862757f},{3,4,3,0.4629100498862757f},{4,3,3,0.4629100498862757f},
    {2,3,3,0.2672612419124244f},{3,2,3,0.2672612419124244f},
    {1,1,4,-0.4629100498862757f},{3,3,4,0.4629100498862757f},{2,4,4,-0.5345224838248488f},{4,2,4,-0.5345224838248488f}}; };

// ---------------- padded x layout helpers ----------------
template<int SEG>
__device__ __forceinline__ int soff(int m) {
    if constexpr (SEG == 0) return m;              // width 1
    else if constexpr (SEG == 1) return 64 + 4*m;  // width 3 padded to 4
    else return 320 + 8*m;                         // width 5 padded to 8
}
template<int L>
__device__ __forceinline__ void load_xvec(const u16* p, float* o) {
    if constexpr (L == 0) {
        o[0] = bf2f(p[0]);
    } else if constexpr (L == 1) {
        uint2 r = *reinterpret_cast<const uint2*>(p);
        o[0] = bf2f((u16)(r.x & 0xffff)); o[1] = bf2f((u16)(r.x >> 16)); o[2] = bf2f((u16)(r.y & 0xffff));
    } else {
        uint4 r = *reinterpret_cast<const uint4*>(p);
        o[0] = bf2f((u16)(r.x & 0xffff)); o[1] = bf2f((u16)(r.x >> 16));
        o[2] = bf2f((u16)(r.y & 0xffff)); o[3] = bf2f((u16)(r.y >> 16));
        o[4] = bf2f((u16)(r.z & 0xffff));
    }
}

// ---------------- LDS staging: one chunk = 4 consecutive u = 32 KiB (R2 layout) -----
// Wt layout: chunk g = pid*16 + (u>>2); 16B unit (w, m=(u&3)*8+h*4+kb) at slot
// w*32 + (m ^ (w&31)). Measured conflict-free on ds_read_b128 (R2/R6/R7: 0 conflicts).
__device__ __forceinline__ void stage_chunk(const u16* __restrict__ Wtb, int g,
                                            u16* lbuf, int tid) {
    const u16* src = Wtb + ((size_t)g << 14);
    #pragma unroll
    for (int qq = 0; qq < 8; ++qq) {
        const int off = qq*2048 + tid*8;       // 16B per thread, lane-linear
        __builtin_amdgcn_global_load_lds(
            (const __attribute__((address_space(1))) void*)(const void*)(src + off),
            (__attribute__((address_space(3))) void*)(void*)(lbuf + off),
            16, 0, 0);
    }
}

// ---------------- one chunk (4 u), consumed by every z-wave; KO kouts share B-frags -
template<int PID, int S1, int S2, int KO>
__device__ __forceinline__ void chunk_compute(const u16* __restrict__ lbuf,
                                              const float (&a1)[4][2*S1+1],
                                              const float (&b2)[16][2*S2+1],
                                              f32x4 (&acc)[KO][4], int lane) {
    const int kb = lane >> 4, nl = lane & 15;
    #pragma unroll
    for (int uu = 0; uu < 4; ++uu) {
        float pre[CGT<PID>::n];
        #pragma unroll
        for (int t = 0; t < CGT<PID>::n; ++t)
            pre[t] = CGT<PID>::e[t].c * a1[uu][CGT<PID>::e[t].i];
        #pragma unroll
        for (int h = 0; h < 2; ++h) {
            bf16x8 bf[4];
            #pragma unroll
            for (int nf = 0; nf < 4; ++nf) {
                const int w = nf*16 + nl;
                const int slot = w*32 + ((uu*8 + h*4 + kb) ^ (w & 31));
                bf[nf] = *reinterpret_cast<const bf16x8*>(lbuf + slot*8);
            }
            #pragma unroll
            for (int ko = 0; ko < KO; ++ko) {
                union { unsigned u[4]; bf16x8 v; } af;
                #pragma unroll
                for (int qq = 0; qq < 4; ++qq) {       // pairwise: short s-liveness
                    float s0 = 0.f, s1 = 0.f;
                    #pragma unroll
                    for (int t = 0; t < CGT<PID>::n; ++t)
                        if (CGT<PID>::e[t].k == ko) {
                            s0 += pre[t] * b2[h*8 + 2*qq    ][CGT<PID>::e[t].j];
                            s1 += pre[t] * b2[h*8 + 2*qq + 1][CGT<PID>::e[t].j];
                        }
                    __hip_bfloat162 t2 = __float22bfloat162_rn(make_float2(s0, s1));
                    unsigned r; __builtin_memcpy(&r, &t2, 4);
                    af.u[qq] = r;
                }
                #pragma unroll
                for (int nf = 0; nf < 4; ++nf)
                    acc[ko][nf] = __builtin_amdgcn_mfma_f32_16x16x32_bf16(af.v, bf[nf], acc[ko][nf], 0, 0, 0);
            }
        }
    }
}

// ---------------- one path: CPP chunks (u = uq*CPP*4 + c*4 + uu), dbuf staging ------
// Per-iter order: barrier -> a1n prefetch (BEFORE stage) -> stage q+1 -> compute q.
// a1n's use waits vmcnt(8) (stage stays in flight); stage q+1 lands under compute q.
template<int PID, int S1, int S2, int KO, int CPP>
__device__ __forceinline__ void run_path(const u16* __restrict__ x1r, const u16* __restrict__ x2r,
                                         const u16* __restrict__ Wtb, u16* lds,
                                         f32x4 (&acc)[KO][4], int lane, int tid, int uq,
                                         int& q, int nq, int GB) {
    constexpr int D1 = 2*S1 + 1, D2 = 2*S2 + 1;
    const int kb = lane >> 4;
    float b2[16][D2];
    #pragma unroll
    for (int h = 0; h < 2; ++h)
        #pragma unroll
        for (int e = 0; e < 8; ++e)
            load_xvec<S2>(x2r + soff<S2>(h*32 + kb*8 + e), b2[h*8 + e]);

    const int ubase = uq*(CPP*4);
    float a1[4][D1], a1n[4][D1];
    #pragma unroll
    for (int uu = 0; uu < 4; ++uu)
        load_xvec<S1>(x1r + soff<S1>(ubase + uu), a1[uu]);

    for (int c = 0; c < CPP; ++c) {
        __syncthreads();                          // chunk q staged; all readers past q^1
        const int cn = (c + 1) & (CPP - 1);       // prefetch next chunk's a1 FIRST
        #pragma unroll
        for (int uu = 0; uu < 4; ++uu)
            load_xvec<S1>(x1r + soff<S1>(ubase + cn*4 + uu), a1n[uu]);
        if (q + 1 < nq) {
            const int qn = q + 1;
            const int g = GB + (qn/CPP)*16 + uq*CPP + (qn%CPP);   // CPP is pow2
            stage_chunk(Wtb, g, lds + ((qn & 1) << 14), tid);
        }
        chunk_compute<PID,S1,S2,KO>(lds + ((q & 1) << 14), a1, b2, acc, lane);
        #pragma unroll
        for (int uu = 0; uu < 4; ++uu)
            #pragma unroll
            for (int d = 0; d < D1; ++d) a1[uu][d] = a1n[uu][d];
        ++q;
    }
}

// ---------------- one unit = (ztile64, io, uq): partials or direct out --------------
template<int IO, int US>
__device__ __forceinline__ void run_unit(const u16* __restrict__ XB1, const u16* __restrict__ XB2,
                                         const u16* __restrict__ Wtb, float* __restrict__ dst,
                                         int zt, int uq, u16* lds) {
    constexpr int KO   = 2*IO + 1;
    constexpr int NP   = (IO == 0) ? 3 : 4;
    constexpr int GB   = (IO == 0) ? 0 : (IO == 1 ? 48 : 112);   // first pid * 16
    constexpr int OFFI = (IO == 0) ? 0 : (IO == 1 ? 64 : 256);
    constexpr int CPP  = 16/US;                   // chunks per path in this block
    const int tid = threadIdx.x;
    const int lane = tid & 63, wave = tid >> 6;   // wave = z-subtile
    const int zin = zt*64 + wave*16 + (lane & 15);
    const u16* x1r = XB1 + (size_t)zin*ROWE;
    const u16* x2r = XB2 + (size_t)zin*ROWE;
    f32x4 acc[KO][4];
    #pragma unroll
    for (int k = 0; k < KO; ++k)
        #pragma unroll
        for (int nf = 0; nf < 4; ++nf) acc[k][nf] = (f32x4){0.f, 0.f, 0.f, 0.f};

    int q = 0;
    stage_chunk(Wtb, GB + uq*CPP, lds, tid);      // prologue: chunk 0 -> buf 0

    if constexpr (IO == 0) {
        run_path<0,0,0,KO,CPP>(x1r, x2r, Wtb, lds, acc, lane, tid, uq, q, NP*CPP, GB);
        run_path<1,1,1,KO,CPP>(x1r, x2r, Wtb, lds, acc, lane, tid, uq, q, NP*CPP, GB);
        run_path<2,2,2,KO,CPP>(x1r, x2r, Wtb, lds, acc, lane, tid, uq, q, NP*CPP, GB);
    } else if constexpr (IO == 1) {
        run_path<3,0,1,KO,CPP>(x1r, x2r, Wtb, lds, acc, lane, tid, uq, q, NP*CPP, GB);
        run_path<4,1,0,KO,CPP>(x1r, x2r, Wtb, lds, acc, lane, tid, uq, q, NP*CPP, GB);
        run_path<5,1,2,KO,CPP>(x1r, x2r, Wtb, lds, acc, lane, tid, uq, q, NP*CPP, GB);
        run_path<6,2,1,KO,CPP>(x1r, x2r, Wtb, lds, acc, lane, tid, uq, q, NP*CPP, GB);
    } else {
        run_path<7,0,2,KO,CPP>(x1r, x2r, Wtb, lds, acc, lane, tid, uq, q, NP*CPP, GB);
        run_path<8,1,1,KO,CPP>(x1r, x2r, Wtb, lds, acc, lane, tid, uq, q, NP*CPP, GB);
        run_path<9,2,0,KO,CPP>(x1r, x2r, Wtb, lds, acc, lane, tid, uq, q, NP*CPP, GB);
        run_path<10,2,2,KO,CPP>(x1r, x2r, Wtb, lds, acc, lane, tid, uq, q, NP*CPP, GB);
    }

    // epilogue: C/D layout col=lane&15 (w), row=(lane>>4)*4+reg (z); no LDS reduction
    const int nl = lane & 15;
    const int zoutb = zt*64 + wave*16 + (lane >> 4)*4;
    #pragma unroll
    for (int k = 0; k < KO; ++k)
        #pragma unroll
        for (int nf = 0; nf < 4; ++nf) {
            const int wcol = nf*16 + nl;
            #pragma unroll
            for (int r = 0; r < 4; ++r) {
                const size_t idx = (size_t)(zoutb + r)*576 + OFFI + wcol*KO + k;
                if constexpr (US == 1) dst[idx] = acc[k][nf][r] * 0.041666666666666664f;
                else                   dst[idx] = acc[k][nf][r];
            }
        }
}

template<int US>
__global__ __launch_bounds__(256) void tp_main(const u16* __restrict__ XB1, const u16* __restrict__ XB2,
                                               const u16* __restrict__ Wtb, float* __restrict__ dst) {
    __shared__ u16 smem[2*16384];                 // 64 KiB, double-buffered 32 KiB chunks
    // unit-major decode: consecutive blocks share the same W slice (L2 residency);
    // io2 (longest) units dispatch first.
    const int unit = blockIdx.x >> 6;             // grid = 64 * 3*US, 64 zt per unit
    const int zt   = blockIdx.x & 63;
    const int io   = 2 - unit / US;
    const int uq   = unit % US;
    float* dstP = (US == 1) ? dst : dst + (size_t)uq*NZ*576;
    if (io == 0)      run_unit<0,US>(XB1, XB2, Wtb, dstP, zt, uq, smem);
    else if (io == 1) run_unit<1,US>(XB1, XB2, Wtb, dstP, zt, uq, smem);
    else              run_unit<2,US>(XB1, XB2, Wtb, dstP, zt, uq, smem);
}

// ---------------- partial-sum reduction (deterministic, f32) ------------------------
template<int US>
__global__ __launch_bounds__(256) void reduce_k(const float* __restrict__ P, float* __restrict__ out) {
    const int i = blockIdx.x*256 + threadIdx.x;   // float4 index; grid sized exactly
    float4 s = reinterpret_cast<const float4*>(P)[i];
    #pragma unroll
    for (int u = 1; u < US; ++u) {
        float4 t = reinterpret_cast<const float4*>(P + (size_t)u*NZ*576)[i];
        s.x += t.x; s.y += t.y; s.z += t.z; s.w += t.w;
    }
    const float sc = 0.041666666666666664f;
    float4 o; o.x = s.x*sc; o.y = s.y*sc; o.z = s.z*sc; o.w = s.w*sc;
    reinterpret_cast<float4*>(out)[i] = o;
}

// ---------------- prep kernels ----------------
// x -> padded bf16 rows [z][ROWE]
__global__ void prep_x(const float* __restrict__ x1, const float* __restrict__ x2,
                       u16* __restrict__ XB1, u16* __restrict__ XB2) {
    int g = blockIdx.x * 256 + threadIdx.x;
    const int PER = NZ * 192;
    if (g >= 2*PER) return;
    const float* src; u16* dst;
    if (g < PER) { src = x1; dst = XB1; } else { src = x2; dst = XB2; g -= PER; }
    const int zz = g / 192, s = g - zz*192, seg = s >> 6, m = s & 63;
    const float* sp = src + zz*576;
    u16* dp = dst + zz*ROWE;
    if (seg == 0) {
        dp[m] = f2bf(sp[m]);
    } else if (seg == 1) {
        u16 t0 = f2bf(sp[64 + m*3 + 0]);
        u16 t1 = f2bf(sp[64 + m*3 + 1]);
        u16 t2 = f2bf(sp[64 + m*3 + 2]);
        uint2 pk; pk.x = (unsigned)t0 | ((unsigned)t1 << 16); pk.y = (unsigned)t2;
        *reinterpret_cast<uint2*>(dp + 64 + m*4) = pk;
    } else {
        u16 t[5];
        #pragma unroll
        for (int c = 0; c < 5; ++c) t[c] = f2bf(sp[256 + m*5 + c]);
        uint4 pk;
        pk.x = (unsigned)t[0] | ((unsigned)t[1] << 16);
        pk.y = (unsigned)t[2] | ((unsigned)t[3] << 16);
        pk.z = (unsigned)t[4];
        pk.w = 0u;
        *reinterpret_cast<uint4*>(dp + 320 + m*8) = pk;
    }
}

// W[p][u][v][w] f32 -> chunked/swizzled bf16 (R2/R7-proven layout):
// chunk g = p*16 + (u>>2); 16B unit (w, m=(u&3)*8 + h*4 + kb) at slot w*32 + (m^(w&31)),
// holding W[p][u][h*32+kb*8+e][w] for e=0..7.
__global__ void prep_w(const float* __restrict__ W, u16* __restrict__ Wtb) {
    __shared__ float ld[4096];
    const int b = blockIdx.x;            // 0..703 : (p,u)
    const int p = b >> 6, u = b & 63;
    const int tid = threadIdx.x;
    const float* src = W + ((size_t)(p*64 + u) << 12);
    #pragma unroll
    for (int i = 0; i < 16; ++i) ld[tid + i*256] = src[tid + i*256];   // coalesced
    __syncthreads();
    const int c = u >> 2, uu = u & 3;
    #pragma unroll
    for (int r = 0; r < 2; ++r) {
        const int j = r*256 + tid;                 // 512 16B-units for this (p,u)
        const int w = j & 63, ms = j >> 6;         // ms = h*4+kb in [0,8)
        const int m = uu*8 + ms;
        const int h = ms >> 2, kb = ms & 3;
        const int vb = h*32 + kb*8;
        u16 tmp[8];
        #pragma unroll
        for (int e = 0; e < 8; ++e) tmp[e] = f2bf(ld[(vb + e)*64 + w]);
        const int s_ = w*32 + (m ^ (w & 31));
        uint4 pk;
        pk.x = (unsigned)tmp[0] | ((unsigned)tmp[1] << 16);
        pk.y = (unsigned)tmp[2] | ((unsigned)tmp[3] << 16);
        pk.z = (unsigned)tmp[4] | ((unsigned)tmp[5] << 16);
        pk.w = (unsigned)tmp[6] | ((unsigned)tmp[7] << 16);
        *reinterpret_cast<uint4*>(Wtb + ((((size_t)(p*16 + c)) << 11) + s_)*8) = pk;
    }
}

extern "C" void kernel_launch(void* const* d_in, const int* in_sizes, int n_in,
                              void* d_out, int out_size, void* d_ws, size_t ws_size,
                              hipStream_t stream) {
    const float* x1 = (const float*)d_in[0];
    const float* x2 = (const float*)d_in[1];
    const float* W  = (const float*)d_in[2];
    float* out = (float*)d_out;

    u16* XB1 = (u16*)d_ws;                 // 4096*832*2  = 6.8 MB
    u16* XB2 = XB1 + NZ*ROWE;              // 6.8 MB
    u16* Wtb = XB2 + NZ*ROWE;              // 11*16*2048*8*2 = 5.8 MB
    const size_t baseu = (size_t)2*NZ*ROWE + (size_t)11*16*2048*8;   // u16 elems
    if (ws_size < baseu*2) return;
    float* Pbuf = (float*)(XB1 + baseu);   // 16B-aligned (baseu*2 % 16 == 0)
    const size_t avail = ws_size - baseu*2;
    const size_t psz = (size_t)NZ*576*4;   // one partial slab, 9.4 MB
    const int US = (avail >= 4*psz) ? 4 : (avail >= 2*psz) ? 2 : 1;

    hipLaunchKernelGGL(prep_x, dim3((2*NZ*192 + 255)/256), dim3(256), 0, stream, x1, x2, XB1, XB2);
    hipLaunchKernelGGL(prep_w, dim3(11*64), dim3(256), 0, stream, W, Wtb);

    const int RED_GRID = NZ*576/4/256;     // 2304, exact
    if (US == 4) {
        hipLaunchKernelGGL(tp_main<4>, dim3(64*12), dim3(256), 0, stream, XB1, XB2, Wtb, Pbuf);
        hipLaunchKernelGGL(reduce_k<4>, dim3(RED_GRID), dim3(256), 0, stream, Pbuf, out);
    } else if (US == 2) {
        hipLaunchKernelGGL(tp_main<2>, dim3(64*6), dim3(256), 0, stream, XB1, XB2, Wtb, Pbuf);
        hipLaunchKernelGGL(reduce_k<2>, dim3(RED_GRID), dim3(256), 0, stream, Pbuf, out);
    } else {
        hipLaunchKernelGGL(tp_main<1>, dim3(64*3), dim3(256), 0, stream, XB1, XB2, Wtb, out);
    }
}

// Round 10
// 129.138 us; speedup vs baseline: 2.9776x; 1.1919x over previous
//
#include <hip/hip_runtime.h>
#include <hip/hip_fp16.h>

// FullyConnectedTensorProduct: irreps 64x(0e+1o+2e) x same -> same, N=4096.
// out[z, OFF[io] + w*(2lo+1) + k] = (1/24) * sum_p sum_{u,v,i,j} W[p][u][v][w]*CG_p[i,j,k]*x1[z,u,i]*x2[z,v,j]
//
// R10 = R9 structure with:
//  (1) f16 packed T-build: v_pk_fma_f16 builds 2 A-elements/inst; result __half2[4]
//      IS the mfma_f32_16x16x32_f16 A-fragment (no cvt/pack stage). x2 j-major so
//      v-pairs load as __half2 directly. CG constants as constexpr f16 bits.
//  (2) balanced 512-block grid: io2 US=4, io1 US=3 (6/5/5 chunks), io0 US=1; io2 first.
//  (3) LDS-bounce epilogue -> contiguous float4 stores (kills 2.5x write amplification);
//      reduce_k is per-column slab-count aware (1/3/4).

typedef unsigned short u16;
typedef _Float16 f16;
typedef __attribute__((ext_vector_type(8))) _Float16 f16x8;   // MFMA A/B frag
typedef __attribute__((ext_vector_type(4))) float f32x4;

#define NZ 4096
#define ROWE 832   // XB1 padded f16 row: seg0 64*1 + seg1 64*4 + seg2 64*8
#define ROW2 576   // XB2 j-major f16 row

__device__ __forceinline__ u16 f2h(float x) {          // RNE f32->f16 (prep kernels)
    _Float16 v = (_Float16)x; u16 b; __builtin_memcpy(&b, &v, 2); return b;
}

// constexpr f32 -> f16 bits (RNE) for CG coefficients (folded at compile time)
constexpr u16 f2h_bits(float xf) {
    unsigned u = __builtin_bit_cast(unsigned, xf);
    unsigned sign = (u >> 16) & 0x8000u;
    int exp = (int)((u >> 23) & 0xffu) - 127 + 15;
    unsigned man = u & 0x7fffffu;
    if (exp >= 31) return (u16)(sign | 0x7c00u);
    if (exp <= 0) {
        if (exp < -10) return (u16)sign;
        man |= 0x800000u;
        int sh = 14 - exp;
        unsigned h = man >> sh;
        unsigned rem = man & ((1u << sh) - 1u);
        unsigned half = 1u << (sh - 1);
        if (rem > half || (rem == half && (h & 1u))) ++h;
        return (u16)(sign | h);
    }
    unsigned h = ((unsigned)exp << 10) | (man >> 13);
    unsigned rem = man & 0x1fffu;
    if (rem > 0x1000u || (rem == 0x1000u && (h & 1u))) ++h;
    return (u16)(sign | h);
}
__device__ __forceinline__ __half2 h2dup(unsigned bits16) {   // dup 16-bit pattern
    unsigned d = bits16 * 0x10001u;
    __half2 r; __builtin_memcpy(&r, &d, 4); return r;
}
__device__ __forceinline__ __half2 h2zero() {
    unsigned z = 0; __half2 r; __builtin_memcpy(&r, &z, 4); return r;
}

// ---------------- Clebsch-Gordan tables (real basis, reference phase conventions) ----
struct CGE { int i, j, k; float c; };
template<int P> struct CGT;
template<> struct CGT<0> { static constexpr int n=1; static constexpr CGE e[1]={{0,0,0,1.0f}}; };
template<> struct CGT<1> { static constexpr int n=3; static constexpr CGE e[3]={
    {0,0,0,0.5773502691896258f},{1,1,0,0.5773502691896258f},{2,2,0,0.5773502691896258f}}; };
template<> struct CGT<2> { static constexpr int n=5; static constexpr CGE e[5]={
    {0,0,0,0.4472135954999579f},{1,1,0,0.4472135954999579f},{2,2,0,0.4472135954999579f},
    {3,3,0,0.4472135954999579f},{4,4,0,0.4472135954999579f}}; };
template<> struct CGT<3> { static constexpr int n=3; static constexpr CGE e[3]={
    {0,0,0,1.0f},{0,1,1,1.0f},{0,2,2,1.0f}}; };
template<> struct CGT<4> { static constexpr int n=3; static constexpr CGE e[3]={
    {0,0,0,1.0f},{1,0,1,1.0f},{2,0,2,1.0f}}; };
template<> struct CGT<5> { static constexpr int n=11; static constexpr CGE e[11]={
    {0,2,0,-0.31622776601683794f},{1,1,0,0.5477225575051661f},{0,4,0,-0.5477225575051661f},{2,0,0,0.5477225575051661f},
    {0,1,1,0.5477225575051661f},{2,3,1,0.5477225575051661f},{1,2,1,0.6324555320336759f},
    {2,2,2,-0.31622776601683794f},{1,3,2,0.5477225575051661f},{0,0,2,0.5477225575051661f},{2,4,2,0.5477225575051661f}}; };
template<> struct CGT<6> { static constexpr int n=11; static constexpr CGE e[11]={
    {2,0,0,-0.31622776601683794f},{1,1,0,0.5477225575051661f},{4,0,0,-0.5477225575051661f},{0,2,0,0.5477225575051661f},
    {1,0,1,0.5477225575051661f},{3,2,1,0.5477225575051661f},{2,1,1,0.6324555320336759f},
    {2,2,2,-0.31622776601683794f},{3,1,2,0.5477225575051661f},{0,0,2,0.5477225575051661f},{4,2,2,0.5477225575051661f}}; };
template<> struct CGT<7> { static constexpr int n=5; static constexpr CGE e[5]={
    {0,0,0,1.0f},{0,1,1,1.0f},{0,2,2,1.0f},{0,3,3,1.0f},{0,4,4,1.0f}}; };
template<> struct CGT<8> { static constexpr int n=11; static constexpr CGE e[11]={
    {0,2,0,0.7071067811865476f},{2,0,0,0.7071067811865476f},
    {0,1,1,0.7071067811865476f},{1,0,1,0.7071067811865476f},
    {0,0,2,-0.4082482904638630f},{1,1,2,0.8164965809277260f},{2,2,2,-0.4082482904638630f},
    {1,2,3,0.7071067811865476f},{2,1,3,0.7071067811865476f},
    {0,0,4,-0.7071067811865476f},{2,2,4,0.7071067811865476f}}; };
template<> struct CGT<9> { static constexpr int n=5; static constexpr CGE e[5]={
    {0,0,0,1.0f},{1,0,1,1.0f},{2,0,2,1.0f},{3,0,3,1.0f},{4,0,4,1.0f}}; };
template<> struct CGT<10> { static constexpr int n=25; static constexpr CGE e[25]={
    {0,2,0,-0.5345224838248488f},{2,0,0,-0.5345224838248488f},{1,3,0,0.4629100498862757f},{3,1,0,0.4629100498862757f},
    {0,3,1,0.4629100498862757f},{3,0,1,0.4629100498862757f},{1,4,1,-0.4629100498862757f},{4,1,1,-0.4629100498862757f},
    {1,2,1,0.2672612419124244f},{2,1,1,0.2672612419124244f},
    {0,0,2,-0.5345224838248488f},{1,1,2,0.2672612419124244f},{2,2,2,0.5345224838248488f},{3,3,2,0.2672612419124244f},{4,4,2,-0.5345224838248488f},
    {0,1,3,0.4629100498862757f},{1,0,3,0.4629100498862757f},{3,4,3,0.4629100498862757f},{4,3,3,0.4629100498862757f},
    {2,3,3,0.2672612419124244f},{3,2,3,0.2672612419124244f},
    {1,1,4,-0.4629100498862757f},{3,3,4,0.4629100498862757f},{2,4,4,-0.5345224838248488f},{4,2,4,-0.5345224838248488f}}; };

// ---------------- x layout helpers ----------------
template<int SEG>
__device__ __forceinline__ int soff(int m) {           // XB1 (x1) padded v-row layout
    if constexpr (SEG == 0) return m;
    else if constexpr (SEG == 1) return 64 + 4*m;
    else return 320 + 8*m;
}
template<int SEG>
__device__ __forceinline__ int sb2(int j) {            // XB2 (x2) j-major layout
    if constexpr (SEG == 0) return 0;
    else if constexpr (SEG == 1) return 64 + j*64;
    else return 256 + j*64;
}
template<int L>
__device__ __forceinline__ void load_a1bits(const u16* p, u16* o) {
    if constexpr (L == 0) {
        o[0] = p[0];
    } else if constexpr (L == 1) {
        uint2 r = *reinterpret_cast<const uint2*>(p);
        o[0] = (u16)(r.x & 0xffff); o[1] = (u16)(r.x >> 16); o[2] = (u16)(r.y & 0xffff);
    } else {
        uint4 r = *reinterpret_cast<const uint4*>(p);
        o[0] = (u16)(r.x & 0xffff); o[1] = (u16)(r.x >> 16);
        o[2] = (u16)(r.y & 0xffff); o[3] = (u16)(r.y >> 16);
        o[4] = (u16)(r.z & 0xffff);
    }
}

// ---------------- LDS staging: one chunk = 4 consecutive u = 32 KiB -----------------
// Wt layout: chunk g = pid*16 + (u>>2); 16B unit (w, m=(u&3)*8+h*4+kb) at slot
// w*32 + (m ^ (w&31)). Conflict-free on ds_read_b128 (R2..R9: 0 conflicts).
__device__ __forceinline__ void stage_chunk(const u16* __restrict__ Wtb, int g,
                                            u16* lbuf, int tid) {
    const u16* src = Wtb + ((size_t)g << 14);
    #pragma unroll
    for (int qq = 0; qq < 8; ++qq) {
        const int off = qq*2048 + tid*8;       // 16B per thread, lane-linear
        __builtin_amdgcn_global_load_lds(
            (const __attribute__((address_space(1))) void*)(const void*)(src + off),
            (__attribute__((address_space(3))) void*)(void*)(lbuf + off),
            16, 0, 0);
    }
}

// ---------------- one chunk (4 u): f16 packed T-build + f16 MFMA --------------------
template<int PID, int S1, int S2, int KO>
__device__ __forceinline__ void chunk_compute(const u16* __restrict__ lbuf,
                                              const u16 (&a1b)[4][2*S1+1],
                                              const __half2 (&b2h)[2][4][2*S2+1],
                                              f32x4 (&acc)[KO][4], int lane) {
    const int kb = lane >> 4, nl = lane & 15;
    #pragma unroll
    for (int uu = 0; uu < 4; ++uu) {
        __half2 a1h[2*S1+1];
        #pragma unroll
        for (int i = 0; i < 2*S1+1; ++i) a1h[i] = h2dup(a1b[uu][i]);
        __half2 pre[CGT<PID>::n];
        #pragma unroll
        for (int t = 0; t < CGT<PID>::n; ++t) {
            const u16 cb = f2h_bits(CGT<PID>::e[t].c);   // compile-time folded
            pre[t] = __hmul2(h2dup(cb), a1h[CGT<PID>::e[t].i]);
        }
        #pragma unroll
        for (int h = 0; h < 2; ++h) {
            f16x8 bf[4];
            #pragma unroll
            for (int nf = 0; nf < 4; ++nf) {
                const int w = nf*16 + nl;
                const int slot = w*32 + ((uu*8 + h*4 + kb) ^ (w & 31));
                bf[nf] = *reinterpret_cast<const f16x8*>(lbuf + slot*8);
            }
            #pragma unroll
            for (int ko = 0; ko < KO; ++ko) {
                union { __half2 h[4]; f16x8 v; } af;
                #pragma unroll
                for (int q = 0; q < 4; ++q) {
                    __half2 s = h2zero();
                    #pragma unroll
                    for (int t = 0; t < CGT<PID>::n; ++t)
                        if (CGT<PID>::e[t].k == ko)
                            s = __hfma2(pre[t], b2h[h][q][CGT<PID>::e[t].j], s);
                    af.h[q] = s;
                }
                #pragma unroll
                for (int nf = 0; nf < 4; ++nf)
                    acc[ko][nf] = __builtin_amdgcn_mfma_f32_16x16x32_f16(af.v, bf[nf], acc[ko][nf], 0, 0, 0);
            }
        }
    }
}

// ---------------- one path: cpp chunks from cbase, dbuf staging ---------------------
template<int PID, int S1, int S2, int KO>
__device__ __forceinline__ void run_path(const u16* __restrict__ x1r, const u16* __restrict__ x2r,
                                         const u16* __restrict__ Wtb, u16* lds,
                                         f32x4 (&acc)[KO][4], int lane, int tid,
                                         int cbase, int cpp, int& q, int nq, int GB) {
    constexpr int D1 = 2*S1 + 1, D2 = 2*S2 + 1;
    const int kb = lane >> 4;
    __half2 b2h[2][4][D2];                         // loop-invariant per path
    #pragma unroll
    for (int h = 0; h < 2; ++h)
        #pragma unroll
        for (int j = 0; j < D2; ++j) {
            const u16* p = x2r + sb2<S2>(j) + h*32 + kb*8;   // 16B aligned
            uint4 r = *reinterpret_cast<const uint4*>(p);
            __builtin_memcpy(&b2h[h][0][j], &r.x, 4);
            __builtin_memcpy(&b2h[h][1][j], &r.y, 4);
            __builtin_memcpy(&b2h[h][2][j], &r.z, 4);
            __builtin_memcpy(&b2h[h][3][j], &r.w, 4);
        }

    const int ubase = cbase*4;
    u16 a1b[4][D1], a1nb[4][D1];
    #pragma unroll
    for (int uu = 0; uu < 4; ++uu)
        load_a1bits<S1>(x1r + soff<S1>(ubase + uu), a1b[uu]);

    for (int c = 0; c < cpp; ++c) {
        __syncthreads();                           // chunk q staged; readers past q^1
        const int cn = (c + 1 == cpp) ? 0 : c + 1; // prefetch next chunk's a1 FIRST
        #pragma unroll
        for (int uu = 0; uu < 4; ++uu)
            load_a1bits<S1>(x1r + soff<S1>(ubase + cn*4 + uu), a1nb[uu]);
        if (q + 1 < nq) {
            const int qn = q + 1;
            const int g = GB + (qn/cpp)*16 + cbase + (qn % cpp);
            stage_chunk(Wtb, g, lds + ((qn & 1) << 14), tid);
        }
        chunk_compute<PID,S1,S2,KO>(lds + ((q & 1) << 14), a1b, b2h, acc, lane);
        #pragma unroll
        for (int uu = 0; uu < 4; ++uu)
            #pragma unroll
            for (int d = 0; d < D1; ++d) a1b[uu][d] = a1nb[uu][d];
        ++q;
    }
}

// ---------------- one unit = (zt, io, u-range): LDS-bounce epilogue -----------------
template<int IO, bool DIRECT>
__device__ __forceinline__ void run_unit(const u16* __restrict__ XB1, const u16* __restrict__ XB2,
                                         const u16* __restrict__ Wtb, float* __restrict__ dst,
                                         int zt, int cbase, int cpp, u16* lds) {
    constexpr int KO   = 2*IO + 1;
    constexpr int NP   = (IO == 0) ? 3 : 4;
    constexpr int GB   = (IO == 0) ? 0 : (IO == 1 ? 48 : 112);   // first pid * 16
    constexpr int OFFI = (IO == 0) ? 0 : (IO == 1 ? 64 : 256);
    constexpr int CO   = KO*64;                   // cols this unit owns
    const int tid = threadIdx.x;
    const int lane = tid & 63, wave = tid >> 6;
    const int zin = zt*64 + wave*16 + (lane & 15);
    const u16* x1r = XB1 + (size_t)zin*ROWE;
    const u16* x2r = XB2 + (size_t)zin*ROW2;
    f32x4 acc[KO][4];
    #pragma unroll
    for (int k = 0; k < KO; ++k)
        #pragma unroll
        for (int nf = 0; nf < 4; ++nf) acc[k][nf] = (f32x4){0.f, 0.f, 0.f, 0.f};

    int q = 0;
    const int nq = NP*cpp;
    stage_chunk(Wtb, GB + cbase, lds, tid);       // prologue: chunk 0 -> buf 0

    if constexpr (IO == 0) {
        run_path<0,0,0,KO>(x1r, x2r, Wtb, lds, acc, lane, tid, cbase, cpp, q, nq, GB);
        run_path<1,1,1,KO>(x1r, x2r, Wtb, lds, acc, lane, tid, cbase, cpp, q, nq, GB);
        run_path<2,2,2,KO>(x1r, x2r, Wtb, lds, acc, lane, tid, cbase, cpp, q, nq, GB);
    } else if constexpr (IO == 1) {
        run_path<3,0,1,KO>(x1r, x2r, Wtb, lds, acc, lane, tid, cbase, cpp, q, nq, GB);
        run_path<4,1,0,KO>(x1r, x2r, Wtb, lds, acc, lane, tid, cbase, cpp, q, nq, GB);
        run_path<5,1,2,KO>(x1r, x2r, Wtb, lds, acc, lane, tid, cbase, cpp, q, nq, GB);
        run_path<6,2,1,KO>(x1r, x2r, Wtb, lds, acc, lane, tid, cbase, cpp, q, nq, GB);
    } else {
        run_path<7,0,2,KO>(x1r, x2r, Wtb, lds, acc, lane, tid, cbase, cpp, q, nq, GB);
        run_path<8,1,1,KO>(x1r, x2r, Wtb, lds, acc, lane, tid, cbase, cpp, q, nq, GB);
        run_path<9,2,0,KO>(x1r, x2r, Wtb, lds, acc, lane, tid, cbase, cpp, q, nq, GB);
        run_path<10,2,2,KO>(x1r, x2r, Wtb, lds, acc, lane, tid, cbase, cpp, q, nq, GB);
    }

    // ---- LDS-bounce epilogue: contiguous float4 global stores ----
    float* lf = reinterpret_cast<float*>(lds);    // 32 z-rows x CO floats (<= 40 KiB)
    const int nl = lane & 15;
    const int hi = lane >> 4;
    #pragma unroll
    for (int round = 0; round < 2; ++round) {
        __syncthreads();                           // LDS free / prev round consumed
        if ((wave >> 1) == round) {
            const int wl = wave & 1;
            const int zl = wl*16 + hi*4;
            #pragma unroll
            for (int k = 0; k < KO; ++k)
                #pragma unroll
                for (int nf = 0; nf < 4; ++nf) {
                    const int col = (nf*16 + nl)*KO + k;
                    #pragma unroll
                    for (int r = 0; r < 4; ++r)
                        lf[(zl + r)*CO + col] = acc[k][nf][r];
                }
        }
        __syncthreads();
        const int zbase = zt*64 + round*32;
        const int TOT4 = 8*CO;                    // 32*CO/4 float4s
        for (int i = tid; i < TOT4; i += 256) {
            const int zr = i / (CO/4), c4 = i % (CO/4);
            float4 v = *reinterpret_cast<const float4*>(&lf[zr*CO + c4*4]);
            if constexpr (DIRECT) {
                const float sc = 0.041666666666666664f;
                v.x *= sc; v.y *= sc; v.z *= sc; v.w *= sc;
            }
            *reinterpret_cast<float4*>(&dst[(size_t)(zbase + zr)*576 + OFFI + c4*4]) = v;
        }
    }
}

template<bool DIRECT>
__global__ __launch_bounds__(256) void tp_main(const u16* __restrict__ XB1, const u16* __restrict__ XB2,
                                               const u16* __restrict__ Wtb, float* __restrict__ dst) {
    __shared__ u16 smem[2*16384];                 // 64 KiB: dbuf staging / bounce scratch
    const int bid = blockIdx.x;
    int io, uq, zt, cbase, cpp;
    if constexpr (DIRECT) {                       // fallback: 192 blocks, full u per block
        io = 2 - (bid >> 6); zt = bid & 63; uq = 0; cbase = 0; cpp = 16;
    } else {                                      // balanced 512 blocks, io2 first
        if (bid < 256)      { io = 2; uq = bid >> 6;         zt = bid & 63; cbase = uq*4; cpp = 4; }
        else if (bid < 448) { int b = bid - 256; io = 1; uq = b >> 6; zt = b & 63;
                              cbase = (uq == 0) ? 0 : (6 + 5*(uq - 1)); cpp = (uq == 0) ? 6 : 5; }
        else                { int b = bid - 448; io = 0; uq = 0; zt = b; cbase = 0; cpp = 16; }
    }
    float* dstP = DIRECT ? dst : dst + (size_t)uq*NZ*576;
    if (io == 0)      run_unit<0,DIRECT>(XB1, XB2, Wtb, dstP, zt, cbase, cpp, smem);
    else if (io == 1) run_unit<1,DIRECT>(XB1, XB2, Wtb, dstP, zt, cbase, cpp, smem);
    else              run_unit<2,DIRECT>(XB1, XB2, Wtb, dstP, zt, cbase, cpp, smem);
}

// ---------------- partial-sum reduction (per-column slab count: 1/3/4) --------------
__global__ __launch_bounds__(256) void reduce_k(const float* __restrict__ P, float* __restrict__ out) {
    const int i = blockIdx.x*256 + threadIdx.x;   // float4 index; grid sized exactly
    const int col0 = (i*4) % 576;
    const int cnt = (col0 < 64) ? 1 : (col0 < 256 ? 3 : 4);
    float4 s = reinterpret_cast<const float4*>(P)[i];
    for (int u = 1; u < cnt; ++u) {
        float4 t = reinterpret_cast<const float4*>(P + (size_t)u*NZ*576)[i];
        s.x += t.x; s.y += t.y; s.z += t.z; s.w += t.w;
    }
    const float sc = 0.041666666666666664f;
    float4 o; o.x = s.x*sc; o.y = s.y*sc; o.z = s.z*sc; o.w = s.w*sc;
    reinterpret_cast<float4*>(out)[i] = o;
}

// ---------------- prep kernels ----------------
// x1 -> XB1 padded f16 rows [z][ROWE]; x2 -> XB2 j-major f16 rows [z][576]
__global__ void prep_x(const float* __restrict__ x1, const float* __restrict__ x2,
                       u16* __restrict__ XB1, u16* __restrict__ XB2) {
    int g = blockIdx.x * 256 + threadIdx.x;
    const int P1 = NZ * 192;
    const int P2 = NZ * 144;
    if (g < P1) {
        const int zz = g / 192, s = g - zz*192, seg = s >> 6, m = s & 63;
        const float* sp = x1 + (size_t)zz*576;
        u16* dp = XB1 + (size_t)zz*ROWE;
        if (seg == 0) {
            dp[m] = f2h(sp[m]);
        } else if (seg == 1) {
            u16 t0 = f2h(sp[64 + m*3 + 0]);
            u16 t1 = f2h(sp[64 + m*3 + 1]);
            u16 t2 = f2h(sp[64 + m*3 + 2]);
            uint2 pk; pk.x = (unsigned)t0 | ((unsigned)t1 << 16); pk.y = (unsigned)t2;
            *reinterpret_cast<uint2*>(dp + 64 + m*4) = pk;
        } else {
            u16 t[5];
            #pragma unroll
            for (int c = 0; c < 5; ++c) t[c] = f2h(sp[256 + m*5 + c]);
            uint4 pk;
            pk.x = (unsigned)t[0] | ((unsigned)t[1] << 16);
            pk.y = (unsigned)t[2] | ((unsigned)t[3] << 16);
            pk.z = (unsigned)t[4];
            pk.w = 0u;
            *reinterpret_cast<uint4*>(dp + 320 + m*8) = pk;
        }
    } else if (g < P1 + P2) {
        const int gg = g - P1;
        const int zz = gg / 144, c4 = gg - zz*144;
        const int col = c4*4;
        const float* sp = x2 + (size_t)zz*576;
        u16 t[4];
        #pragma unroll
        for (int qd = 0; qd < 4; ++qd) {
            const int cc = col + qd;
            int si;
            if (cc < 64)       si = cc;
            else if (cc < 256) { const int j = (cc - 64) >> 6, v = (cc - 64) & 63;  si = 64  + v*3 + j; }
            else               { const int j = (cc - 256) >> 6, v = (cc - 256) & 63; si = 256 + v*5 + j; }
            t[qd] = f2h(sp[si]);
        }
        uint2 pk;
        pk.x = (unsigned)t[0] | ((unsigned)t[1] << 16);
        pk.y = (unsigned)t[2] | ((unsigned)t[3] << 16);
        *reinterpret_cast<uint2*>(XB2 + (size_t)zz*ROW2 + col) = pk;
    }
}

// W[p][u][v][w] f32 -> chunked/swizzled f16 (same layout as R9, f16 payload):
// chunk g = p*16 + (u>>2); 16B unit (w, m=(u&3)*8 + h*4 + kb) at slot w*32 + (m^(w&31)),
// holding W[p][u][h*32+kb*8+e][w] for e=0..7.
__global__ void prep_w(const float* __restrict__ W, u16* __restrict__ Wtb) {
    __shared__ float ld[4096];
    const int b = blockIdx.x;            // 0..703 : (p,u)
    const int p = b >> 6, u = b & 63;
    const int tid = threadIdx.x;
    const float* src = W + ((size_t)(p*64 + u) << 12);
    #pragma unroll
    for (int i = 0; i < 16; ++i) ld[tid + i*256] = src[tid + i*256];   // coalesced
    __syncthreads();
    const int c = u >> 2, uu = u & 3;
    #pragma unroll
    for (int r = 0; r < 2; ++r) {
        const int j = r*256 + tid;                 // 512 16B-units for this (p,u)
        const int w = j & 63, ms = j >> 6;         // ms = h*4+kb in [0,8)
        const int m = uu*8 + ms;
        const int h = ms >> 2, kb = ms & 3;
        const int vb = h*32 + kb*8;
        u16 tmp[8];
        #pragma unroll
        for (int e = 0; e < 8; ++e) tmp[e] = f2h(ld[(vb + e)*64 + w]);
        const int s_ = w*32 + (m ^ (w & 31));
        uint4 pk;
        pk.x = (unsigned)tmp[0] | ((unsigned)tmp[1] << 16);
        pk.y = (unsigned)tmp[2] | ((unsigned)tmp[3] << 16);
        pk.z = (unsigned)tmp[4] | ((unsigned)tmp[5] << 16);
        pk.w = (unsigned)tmp[6] | ((unsigned)tmp[7] << 16);
        *reinterpret_cast<uint4*>(Wtb + ((((size_t)(p*16 + c)) << 11) + s_)*8) = pk;
    }
}

extern "C" void kernel_launch(void* const* d_in, const int* in_sizes, int n_in,
                              void* d_out, int out_size, void* d_ws, size_t ws_size,
                              hipStream_t stream) {
    const float* x1 = (const float*)d_in[0];
    const float* x2 = (const float*)d_in[1];
    const float* W  = (const float*)d_in[2];
    float* out = (float*)d_out;

    u16* XB1 = (u16*)d_ws;                         // 4096*832*2 = 6.8 MB
    u16* XB2 = XB1 + (size_t)NZ*ROWE;              // 4096*576*2 = 4.7 MB
    u16* Wtb = XB2 + (size_t)NZ*ROW2;              // 11*16*2048*8*2 = 5.8 MB
    const size_t baseu = (size_t)NZ*ROWE + (size_t)NZ*ROW2 + (size_t)11*16*2048*8;  // u16
    if (ws_size < baseu*2) return;
    float* Pbuf = (float*)(XB1 + baseu);           // 16B-aligned (baseu*2 % 16 == 0)
    const size_t avail = ws_size - baseu*2;
    const size_t psz = (size_t)NZ*576*4;           // one partial slab, 9.4 MB
    const bool balanced = (avail >= 4*psz);

    hipLaunchKernelGGL(prep_x, dim3((NZ*(192+144))/256), dim3(256), 0, stream, x1, x2, XB1, XB2);
    hipLaunchKernelGGL(prep_w, dim3(11*64), dim3(256), 0, stream, W, Wtb);

    if (balanced) {
        hipLaunchKernelGGL(tp_main<false>, dim3(512), dim3(256), 0, stream, XB1, XB2, Wtb, Pbuf);
        hipLaunchKernelGGL(reduce_k, dim3(NZ*576/4/256), dim3(256), 0, stream, Pbuf, out);
    } else {
        hipLaunchKernelGGL(tp_main<true>, dim3(192), dim3(256), 0, stream, XB1, XB2, Wtb, out);
    }
}

// Round 11
// 112.680 us; speedup vs baseline: 3.4125x; 1.1461x over previous
//
#include <hip/hip_runtime.h>
#include <hip/hip_fp16.h>

// FullyConnectedTensorProduct: irreps 64x(0e+1o+2e) x same -> same, N=4096.
// out[z, OFF[io] + w*(2lo+1) + k] = (1/24) * sum_p sum_{u,v,i,j} W[p][u][v][w]*CG_p[i,j,k]*x1[z,u,i]*x2[z,v,j]
//
// R11 = R10 (f16 packed T-build, balanced 512 grid, LDS-bounce epilogue, partials+reduce)
// with chunk = 2u (16 KiB) and dbuf LDS = 32 KiB -> 3 blocks/CU (12 waves/CU) at the
// natural VGPR count (NO forced launch bound -- R8's spill lesson). Epilogue bounce is
// 4 rounds x 16 z-rows (<= 20 KiB). Total staged W bytes unchanged.

typedef unsigned short u16;
typedef _Float16 f16;
typedef __attribute__((ext_vector_type(8))) _Float16 f16x8;   // MFMA A/B frag
typedef __attribute__((ext_vector_type(4))) float f32x4;

#define NZ 4096
#define ROWE 832   // XB1 padded f16 row: seg0 64*1 + seg1 64*4 + seg2 64*8
#define ROW2 576   // XB2 j-major f16 row

__device__ __forceinline__ u16 f2h(float x) {          // RNE f32->f16 (prep kernels)
    _Float16 v = (_Float16)x; u16 b; __builtin_memcpy(&b, &v, 2); return b;
}

// constexpr f32 -> f16 bits (RNE) for CG coefficients (folded at compile time)
constexpr u16 f2h_bits(float xf) {
    unsigned u = __builtin_bit_cast(unsigned, xf);
    unsigned sign = (u >> 16) & 0x8000u;
    int exp = (int)((u >> 23) & 0xffu) - 127 + 15;
    unsigned man = u & 0x7fffffu;
    if (exp >= 31) return (u16)(sign | 0x7c00u);
    if (exp <= 0) {
        if (exp < -10) return (u16)sign;
        man |= 0x800000u;
        int sh = 14 - exp;
        unsigned h = man >> sh;
        unsigned rem = man & ((1u << sh) - 1u);
        unsigned half = 1u << (sh - 1);
        if (rem > half || (rem == half && (h & 1u))) ++h;
        return (u16)(sign | h);
    }
    unsigned h = ((unsigned)exp << 10) | (man >> 13);
    unsigned rem = man & 0x1fffu;
    if (rem > 0x1000u || (rem == 0x1000u && (h & 1u))) ++h;
    return (u16)(sign | h);
}
__device__ __forceinline__ __half2 h2dup(unsigned bits16) {   // dup 16-bit pattern
    unsigned d = bits16 * 0x10001u;
    __half2 r; __builtin_memcpy(&r, &d, 4); return r;
}
__device__ __forceinline__ __half2 h2zero() {
    unsigned z = 0; __half2 r; __builtin_memcpy(&r, &z, 4); return r;
}

// ---------------- Clebsch-Gordan tables (real basis, reference phase conventions) ----
struct CGE { int i, j, k; float c; };
template<int P> struct CGT;
template<> struct CGT<0> { static constexpr int n=1; static constexpr CGE e[1]={{0,0,0,1.0f}}; };
template<> struct CGT<1> { static constexpr int n=3; static constexpr CGE e[3]={
    {0,0,0,0.5773502691896258f},{1,1,0,0.5773502691896258f},{2,2,0,0.5773502691896258f}}; };
template<> struct CGT<2> { static constexpr int n=5; static constexpr CGE e[5]={
    {0,0,0,0.4472135954999579f},{1,1,0,0.4472135954999579f},{2,2,0,0.4472135954999579f},
    {3,3,0,0.4472135954999579f},{4,4,0,0.4472135954999579f}}; };
template<> struct CGT<3> { static constexpr int n=3; static constexpr CGE e[3]={
    {0,0,0,1.0f},{0,1,1,1.0f},{0,2,2,1.0f}}; };
template<> struct CGT<4> { static constexpr int n=3; static constexpr CGE e[3]={
    {0,0,0,1.0f},{1,0,1,1.0f},{2,0,2,1.0f}}; };
template<> struct CGT<5> { static constexpr int n=11; static constexpr CGE e[11]={
    {0,2,0,-0.31622776601683794f},{1,1,0,0.5477225575051661f},{0,4,0,-0.5477225575051661f},{2,0,0,0.5477225575051661f},
    {0,1,1,0.5477225575051661f},{2,3,1,0.5477225575051661f},{1,2,1,0.6324555320336759f},
    {2,2,2,-0.31622776601683794f},{1,3,2,0.5477225575051661f},{0,0,2,0.5477225575051661f},{2,4,2,0.5477225575051661f}}; };
template<> struct CGT<6> { static constexpr int n=11; static constexpr CGE e[11]={
    {2,0,0,-0.31622776601683794f},{1,1,0,0.5477225575051661f},{4,0,0,-0.5477225575051661f},{0,2,0,0.5477225575051661f},
    {1,0,1,0.5477225575051661f},{3,2,1,0.5477225575051661f},{2,1,1,0.6324555320336759f},
    {2,2,2,-0.31622776601683794f},{3,1,2,0.5477225575051661f},{0,0,2,0.5477225575051661f},{4,2,2,0.5477225575051661f}}; };
template<> struct CGT<7> { static constexpr int n=5; static constexpr CGE e[5]={
    {0,0,0,1.0f},{0,1,1,1.0f},{0,2,2,1.0f},{0,3,3,1.0f},{0,4,4,1.0f}}; };
template<> struct CGT<8> { static constexpr int n=11; static constexpr CGE e[11]={
    {0,2,0,0.7071067811865476f},{2,0,0,0.7071067811865476f},
    {0,1,1,0.7071067811865476f},{1,0,1,0.7071067811865476f},
    {0,0,2,-0.4082482904638630f},{1,1,2,0.8164965809277260f},{2,2,2,-0.4082482904638630f},
    {1,2,3,0.7071067811865476f},{2,1,3,0.7071067811865476f},
    {0,0,4,-0.7071067811865476f},{2,2,4,0.7071067811865476f}}; };
template<> struct CGT<9> { static constexpr int n=5; static constexpr CGE e[5]={
    {0,0,0,1.0f},{1,0,1,1.0f},{2,0,2,1.0f},{3,0,3,1.0f},{4,0,4,1.0f}}; };
template<> struct CGT<10> { static constexpr int n=25; static constexpr CGE e[25]={
    {0,2,0,-0.5345224838248488f},{2,0,0,-0.5345224838248488f},{1,3,0,0.4629100498862757f},{3,1,0,0.4629100498862757f},
    {0,3,1,0.4629100498862757f},{3,0,1,0.4629100498862757f},{1,4,1,-0.4629100498862757f},{4,1,1,-0.4629100498862757f},
    {1,2,1,0.2672612419124244f},{2,1,1,0.2672612419124244f},
    {0,0,2,-0.5345224838248488f},{1,1,2,0.2672612419124244f},{2,2,2,0.5345224838248488f},{3,3,2,0.2672612419124244f},{4,4,2,-0.5345224838248488f},
    {0,1,3,0.4629100498862757f},{1,0,3,0.4629100498862757f},{3,4,3,0.4629100498862757f},{4,3,3,0.4629100498862757f},
    {2,3,3,0.2672612419124244f},{3,2,3,0.2672612419124244f},
    {1,1,4,-0.4629100498862757f},{3,3,4,0.4629100498862757f},{2,4,4,-0.5345224838248488f},{4,2,4,-0.5345224838248488f}}; };

// ---------------- x layout helpers ----------------
template<int SEG>
__device__ __forceinline__ int soff(int m) {           // XB1 (x1) padded v-row layout
    if constexpr (SEG == 0) return m;
    else if constexpr (SEG == 1) return 64 + 4*m;
    else return 320 + 8*m;
}
template<int SEG>
__device__ __forceinline__ int sb2(int j) {            // XB2 (x2) j-major layout
    if constexpr (SEG == 0) return 0;
    else if constexpr (SEG == 1) return 64 + j*64;
    else return 256 + j*64;
}
template<int L>
__device__ __forceinline__ void load_a1bits(const u16* p, u16* o) {
    if constexpr (L == 0) {
        o[0] = p[0];
    } else if constexpr (L == 1) {
        uint2 r = *reinterpret_cast<const uint2*>(p);
        o[0] = (u16)(r.x & 0xffff); o[1] = (u16)(r.x >> 16); o[2] = (u16)(r.y & 0xffff);
    } else {
        uint4 r = *reinterpret_cast<const uint4*>(p);
        o[0] = (u16)(r.x & 0xffff); o[1] = (u16)(r.x >> 16);
        o[2] = (u16)(r.y & 0xffff); o[3] = (u16)(r.y >> 16);
        o[4] = (u16)(r.z & 0xffff);
    }
}

// ---------------- LDS staging: one chunk = 2 consecutive u = 16 KiB -----------------
// Wt layout: chunk g = pid*32 + (u>>1); 16B unit (w, m=(u&1)*8+h*4+kb) at slot
// w*16 + (m ^ (w&15)). Conflict-free on ds_read_b128 (R8 measured 0 conflicts).
__device__ __forceinline__ void stage_chunk(const u16* __restrict__ Wtb, int g,
                                            u16* lbuf, int tid) {
    const u16* src = Wtb + ((size_t)g << 13);
    #pragma unroll
    for (int qq = 0; qq < 4; ++qq) {
        const int off = qq*2048 + tid*8;       // 16B per thread, lane-linear
        __builtin_amdgcn_global_load_lds(
            (const __attribute__((address_space(1))) void*)(const void*)(src + off),
            (__attribute__((address_space(3))) void*)(void*)(lbuf + off),
            16, 0, 0);
    }
}

// ---------------- one chunk (2 u): f16 packed T-build + f16 MFMA --------------------
template<int PID, int S1, int S2, int KO>
__device__ __forceinline__ void chunk_compute(const u16* __restrict__ lbuf,
                                              const u16 (&a1b)[2][2*S1+1],
                                              const __half2 (&b2h)[2][4][2*S2+1],
                                              f32x4 (&acc)[KO][4], int lane) {
    const int kb = lane >> 4, nl = lane & 15;
    #pragma unroll
    for (int uu = 0; uu < 2; ++uu) {
        __half2 a1h[2*S1+1];
        #pragma unroll
        for (int i = 0; i < 2*S1+1; ++i) a1h[i] = h2dup(a1b[uu][i]);
        __half2 pre[CGT<PID>::n];
        #pragma unroll
        for (int t = 0; t < CGT<PID>::n; ++t) {
            const u16 cb = f2h_bits(CGT<PID>::e[t].c);   // compile-time folded
            pre[t] = __hmul2(h2dup(cb), a1h[CGT<PID>::e[t].i]);
        }
        #pragma unroll
        for (int h = 0; h < 2; ++h) {
            f16x8 bf[4];
            #pragma unroll
            for (int nf = 0; nf < 4; ++nf) {
                const int w = nf*16 + nl;
                const int slot = w*16 + ((uu*8 + h*4 + kb) ^ (w & 15));
                bf[nf] = *reinterpret_cast<const f16x8*>(lbuf + slot*8);
            }
            #pragma unroll
            for (int ko = 0; ko < KO; ++ko) {
                union { __half2 h[4]; f16x8 v; } af;
                #pragma unroll
                for (int q = 0; q < 4; ++q) {
                    __half2 s = h2zero();
                    #pragma unroll
                    for (int t = 0; t < CGT<PID>::n; ++t)
                        if (CGT<PID>::e[t].k == ko)
                            s = __hfma2(pre[t], b2h[h][q][CGT<PID>::e[t].j], s);
                    af.h[q] = s;
                }
                #pragma unroll
                for (int nf = 0; nf < 4; ++nf)
                    acc[ko][nf] = __builtin_amdgcn_mfma_f32_16x16x32_f16(af.v, bf[nf], acc[ko][nf], 0, 0, 0);
            }
        }
    }
}

// ---------------- one path: cpp chunks from cbase, dbuf staging ---------------------
template<int PID, int S1, int S2, int KO>
__device__ __forceinline__ void run_path(const u16* __restrict__ x1r, const u16* __restrict__ x2r,
                                         const u16* __restrict__ Wtb, u16* lds,
                                         f32x4 (&acc)[KO][4], int lane, int tid,
                                         int cbase, int cpp, int& q, int nq, int GB) {
    constexpr int D1 = 2*S1 + 1, D2 = 2*S2 + 1;
    const int kb = lane >> 4;
    __half2 b2h[2][4][D2];                         // loop-invariant per path
    #pragma unroll
    for (int h = 0; h < 2; ++h)
        #pragma unroll
        for (int j = 0; j < D2; ++j) {
            const u16* p = x2r + sb2<S2>(j) + h*32 + kb*8;   // 16B aligned
            uint4 r = *reinterpret_cast<const uint4*>(p);
            __builtin_memcpy(&b2h[h][0][j], &r.x, 4);
            __builtin_memcpy(&b2h[h][1][j], &r.y, 4);
            __builtin_memcpy(&b2h[h][2][j], &r.z, 4);
            __builtin_memcpy(&b2h[h][3][j], &r.w, 4);
        }

    const int ubase = cbase*2;
    u16 a1b[2][D1], a1nb[2][D1];
    #pragma unroll
    for (int uu = 0; uu < 2; ++uu)
        load_a1bits<S1>(x1r + soff<S1>(ubase + uu), a1b[uu]);

    for (int c = 0; c < cpp; ++c) {
        __syncthreads();                           // chunk q staged; readers past q^1
        const int cn = (c + 1 == cpp) ? 0 : c + 1; // prefetch next chunk's a1 FIRST
        #pragma unroll
        for (int uu = 0; uu < 2; ++uu)
            load_a1bits<S1>(x1r + soff<S1>(ubase + cn*2 + uu), a1nb[uu]);
        if (q + 1 < nq) {
            const int qn = q + 1;
            const int g = GB + (qn/cpp)*32 + cbase + (qn % cpp);
            stage_chunk(Wtb, g, lds + ((qn & 1) << 13), tid);
        }
        chunk_compute<PID,S1,S2,KO>(lds + ((q & 1) << 13), a1b, b2h, acc, lane);
        #pragma unroll
        for (int uu = 0; uu < 2; ++uu)
            #pragma unroll
            for (int d = 0; d < D1; ++d) a1b[uu][d] = a1nb[uu][d];
        ++q;
    }
}

// ---------------- one unit = (zt, io, u-range): LDS-bounce epilogue -----------------
template<int IO, bool DIRECT>
__device__ __forceinline__ void run_unit(const u16* __restrict__ XB1, const u16* __restrict__ XB2,
                                         const u16* __restrict__ Wtb, float* __restrict__ dst,
                                         int zt, int cbase, int cpp, u16* lds) {
    constexpr int KO   = 2*IO + 1;
    constexpr int NP   = (IO == 0) ? 3 : 4;
    constexpr int GB   = (IO == 0) ? 0 : (IO == 1 ? 96 : 224);   // first pid * 32
    constexpr int OFFI = (IO == 0) ? 0 : (IO == 1 ? 64 : 256);
    constexpr int CO   = KO*64;                   // cols this unit owns
    const int tid = threadIdx.x;
    const int lane = tid & 63, wave = tid >> 6;
    const int zin = zt*64 + wave*16 + (lane & 15);
    const u16* x1r = XB1 + (size_t)zin*ROWE;
    const u16* x2r = XB2 + (size_t)zin*ROW2;
    f32x4 acc[KO][4];
    #pragma unroll
    for (int k = 0; k < KO; ++k)
        #pragma unroll
        for (int nf = 0; nf < 4; ++nf) acc[k][nf] = (f32x4){0.f, 0.f, 0.f, 0.f};

    int q = 0;
    const int nq = NP*cpp;
    stage_chunk(Wtb, GB + cbase, lds, tid);       // prologue: chunk 0 -> buf 0

    if constexpr (IO == 0) {
        run_path<0,0,0,KO>(x1r, x2r, Wtb, lds, acc, lane, tid, cbase, cpp, q, nq, GB);
        run_path<1,1,1,KO>(x1r, x2r, Wtb, lds, acc, lane, tid, cbase, cpp, q, nq, GB);
        run_path<2,2,2,KO>(x1r, x2r, Wtb, lds, acc, lane, tid, cbase, cpp, q, nq, GB);
    } else if constexpr (IO == 1) {
        run_path<3,0,1,KO>(x1r, x2r, Wtb, lds, acc, lane, tid, cbase, cpp, q, nq, GB);
        run_path<4,1,0,KO>(x1r, x2r, Wtb, lds, acc, lane, tid, cbase, cpp, q, nq, GB);
        run_path<5,1,2,KO>(x1r, x2r, Wtb, lds, acc, lane, tid, cbase, cpp, q, nq, GB);
        run_path<6,2,1,KO>(x1r, x2r, Wtb, lds, acc, lane, tid, cbase, cpp, q, nq, GB);
    } else {
        run_path<7,0,2,KO>(x1r, x2r, Wtb, lds, acc, lane, tid, cbase, cpp, q, nq, GB);
        run_path<8,1,1,KO>(x1r, x2r, Wtb, lds, acc, lane, tid, cbase, cpp, q, nq, GB);
        run_path<9,2,0,KO>(x1r, x2r, Wtb, lds, acc, lane, tid, cbase, cpp, q, nq, GB);
        run_path<10,2,2,KO>(x1r, x2r, Wtb, lds, acc, lane, tid, cbase, cpp, q, nq, GB);
    }

    // ---- LDS-bounce epilogue: 4 rounds x 16 z-rows (<= 20 KiB), float4 stores ----
    float* lf = reinterpret_cast<float*>(lds);
    const int nl = lane & 15;
    const int hi = lane >> 4;
    #pragma unroll
    for (int round = 0; round < 4; ++round) {
        __syncthreads();                           // LDS free / prev round consumed
        if (wave == round) {
            const int zl = hi*4;
            #pragma unroll
            for (int k = 0; k < KO; ++k)
                #pragma unroll
                for (int nf = 0; nf < 4; ++nf) {
                    const int col = (nf*16 + nl)*KO + k;
                    #pragma unroll
                    for (int r = 0; r < 4; ++r)
                        lf[(zl + r)*CO + col] = acc[k][nf][r];
                }
        }
        __syncthreads();
        const int zbase = zt*64 + round*16;
        const int TOT4 = 4*CO;                    // 16*CO/4 float4s
        for (int i = tid; i < TOT4; i += 256) {
            const int zr = i / (CO/4), c4 = i % (CO/4);
            float4 v = *reinterpret_cast<const float4*>(&lf[zr*CO + c4*4]);
            if constexpr (DIRECT) {
                const float sc = 0.041666666666666664f;
                v.x *= sc; v.y *= sc; v.z *= sc; v.w *= sc;
            }
            *reinterpret_cast<float4*>(&dst[(size_t)(zbase + zr)*576 + OFFI + c4*4]) = v;
        }
    }
}

template<bool DIRECT>
__global__ __launch_bounds__(256) void tp_main(const u16* __restrict__ XB1, const u16* __restrict__ XB2,
                                               const u16* __restrict__ Wtb, float* __restrict__ dst) {
    __shared__ u16 smem[2*8192];                  // 32 KiB: dbuf staging / bounce scratch
    const int bid = blockIdx.x;
    int io, uq, zt, cbase, cpp;
    if constexpr (DIRECT) {                       // fallback: 192 blocks, full u per block
        io = 2 - (bid >> 6); zt = bid & 63; uq = 0; cbase = 0; cpp = 32;
    } else {                                      // balanced 512 blocks, io2 first
        if (bid < 256)      { io = 2; uq = bid >> 6;         zt = bid & 63; cbase = uq*8; cpp = 8; }
        else if (bid < 448) { int b = bid - 256; io = 1; uq = b >> 6; zt = b & 63;
                              cbase = (uq == 0) ? 0 : (11 + 11*(uq - 1)); cpp = (uq == 2) ? 10 : 11; }
        else                { int b = bid - 448; io = 0; uq = 0; zt = b; cbase = 0; cpp = 32; }
    }
    float* dstP = DIRECT ? dst : dst + (size_t)uq*NZ*576;
    if (io == 0)      run_unit<0,DIRECT>(XB1, XB2, Wtb, dstP, zt, cbase, cpp, smem);
    else if (io == 1) run_unit<1,DIRECT>(XB1, XB2, Wtb, dstP, zt, cbase, cpp, smem);
    else              run_unit<2,DIRECT>(XB1, XB2, Wtb, dstP, zt, cbase, cpp, smem);
}

// ---------------- partial-sum reduction (per-column slab count: 1/3/4) --------------
__global__ __launch_bounds__(256) void reduce_k(const float* __restrict__ P, float* __restrict__ out) {
    const int i = blockIdx.x*256 + threadIdx.x;   // float4 index; grid sized exactly
    const int col0 = (i*4) % 576;
    const int cnt = (col0 < 64) ? 1 : (col0 < 256 ? 3 : 4);
    float4 s = reinterpret_cast<const float4*>(P)[i];
    for (int u = 1; u < cnt; ++u) {
        float4 t = reinterpret_cast<const float4*>(P + (size_t)u*NZ*576)[i];
        s.x += t.x; s.y += t.y; s.z += t.z; s.w += t.w;
    }
    const float sc = 0.041666666666666664f;
    float4 o; o.x = s.x*sc; o.y = s.y*sc; o.z = s.z*sc; o.w = s.w*sc;
    reinterpret_cast<float4*>(out)[i] = o;
}

// ---------------- prep kernels ----------------
// x1 -> XB1 padded f16 rows [z][ROWE]; x2 -> XB2 j-major f16 rows [z][576]
__global__ void prep_x(const float* __restrict__ x1, const float* __restrict__ x2,
                       u16* __restrict__ XB1, u16* __restrict__ XB2) {
    int g = blockIdx.x * 256 + threadIdx.x;
    const int P1 = NZ * 192;
    const int P2 = NZ * 144;
    if (g < P1) {
        const int zz = g / 192, s = g - zz*192, seg = s >> 6, m = s & 63;
        const float* sp = x1 + (size_t)zz*576;
        u16* dp = XB1 + (size_t)zz*ROWE;
        if (seg == 0) {
            dp[m] = f2h(sp[m]);
        } else if (seg == 1) {
            u16 t0 = f2h(sp[64 + m*3 + 0]);
            u16 t1 = f2h(sp[64 + m*3 + 1]);
            u16 t2 = f2h(sp[64 + m*3 + 2]);
            uint2 pk; pk.x = (unsigned)t0 | ((unsigned)t1 << 16); pk.y = (unsigned)t2;
            *reinterpret_cast<uint2*>(dp + 64 + m*4) = pk;
        } else {
            u16 t[5];
            #pragma unroll
            for (int c = 0; c < 5; ++c) t[c] = f2h(sp[256 + m*5 + c]);
            uint4 pk;
            pk.x = (unsigned)t[0] | ((unsigned)t[1] << 16);
            pk.y = (unsigned)t[2] | ((unsigned)t[3] << 16);
            pk.z = (unsigned)t[4];
            pk.w = 0u;
            *reinterpret_cast<uint4*>(dp + 320 + m*8) = pk;
        }
    } else if (g < P1 + P2) {
        const int gg = g - P1;
        const int zz = gg / 144, c4 = gg - zz*144;
        const int col = c4*4;
        const float* sp = x2 + (size_t)zz*576;
        u16 t[4];
        #pragma unroll
        for (int qd = 0; qd < 4; ++qd) {
            const int cc = col + qd;
            int si;
            if (cc < 64)       si = cc;
            else if (cc < 256) { const int j = (cc - 64) >> 6, v = (cc - 64) & 63;  si = 64  + v*3 + j; }
            else               { const int j = (cc - 256) >> 6, v = (cc - 256) & 63; si = 256 + v*5 + j; }
            t[qd] = f2h(sp[si]);
        }
        uint2 pk;
        pk.x = (unsigned)t[0] | ((unsigned)t[1] << 16);
        pk.y = (unsigned)t[2] | ((unsigned)t[3] << 16);
        *reinterpret_cast<uint2*>(XB2 + (size_t)zz*ROW2 + col) = pk;
    }
}

// W[p][u][v][w] f32 -> chunked/swizzled f16 (16 KiB chunks):
// chunk g = p*32 + (u>>1); 16B unit (w, m=(u&1)*8 + h*4 + kb) at slot w*16 + (m^(w&15)),
// holding W[p][u][h*32+kb*8+e][w] for e=0..7.
__global__ void prep_w(const float* __restrict__ W, u16* __restrict__ Wtb) {
    __shared__ float ld[4096];
    const int b = blockIdx.x;            // 0..703 : (p,u)
    const int p = b >> 6, u = b & 63;
    const int tid = threadIdx.x;
    const float* src = W + ((size_t)(p*64 + u) << 12);
    #pragma unroll
    for (int i = 0; i < 16; ++i) ld[tid + i*256] = src[tid + i*256];   // coalesced
    __syncthreads();
    const int g  = p*32 + (u >> 1);
    const int mb = (u & 1)*8;
    #pragma unroll
    for (int r = 0; r < 2; ++r) {
        const int j = r*256 + tid;                 // 512 16B-units for this (p,u)
        const int w = j & 63, ms = j >> 6;         // ms = h*4+kb in [0,8)
        const int m = mb + ms;
        const int h = ms >> 2, kb = ms & 3;
        const int vb = h*32 + kb*8;
        u16 tmp[8];
        #pragma unroll
        for (int e = 0; e < 8; ++e) tmp[e] = f2h(ld[(vb + e)*64 + w]);
        const int unit = w*16 + (m ^ (w & 15));
        uint4 pk;
        pk.x = (unsigned)tmp[0] | ((unsigned)tmp[1] << 16);
        pk.y = (unsigned)tmp[2] | ((unsigned)tmp[3] << 16);
        pk.z = (unsigned)tmp[4] | ((unsigned)tmp[5] << 16);
        pk.w = (unsigned)tmp[6] | ((unsigned)tmp[7] << 16);
        *reinterpret_cast<uint4*>(Wtb + (size_t)g*8192 + (size_t)unit*8) = pk;
    }
}

extern "C" void kernel_launch(void* const* d_in, const int* in_sizes, int n_in,
                              void* d_out, int out_size, void* d_ws, size_t ws_size,
                              hipStream_t stream) {
    const float* x1 = (const float*)d_in[0];
    const float* x2 = (const float*)d_in[1];
    const float* W  = (const float*)d_in[2];
    float* out = (float*)d_out;

    u16* XB1 = (u16*)d_ws;                         // 4096*832*2 = 6.8 MB
    u16* XB2 = XB1 + (size_t)NZ*ROWE;              // 4096*576*2 = 4.7 MB
    u16* Wtb = XB2 + (size_t)NZ*ROW2;              // 11*32*8192*2 = 5.8 MB
    const size_t baseu = (size_t)NZ*ROWE + (size_t)NZ*ROW2 + (size_t)11*32*8192;  // u16
    if (ws_size < baseu*2) return;
    float* Pbuf = (float*)(XB1 + baseu);           // 16B-aligned (baseu*2 % 16 == 0)
    const size_t avail = ws_size - baseu*2;
    const size_t psz = (size_t)NZ*576*4;           // one partial slab, 9.4 MB
    const bool balanced = (avail >= 4*psz);

    hipLaunchKernelGGL(prep_x, dim3((NZ*(192+144))/256), dim3(256), 0, stream, x1, x2, XB1, XB2);
    hipLaunchKernelGGL(prep_w, dim3(11*64), dim3(256), 0, stream, W, Wtb);

    if (balanced) {
        hipLaunchKernelGGL(tp_main<false>, dim3(512), dim3(256), 0, stream, XB1, XB2, Wtb, Pbuf);
        hipLaunchKernelGGL(reduce_k, dim3(NZ*576/4/256), dim3(256), 0, stream, Pbuf, out);
    } else {
        hipLaunchKernelGGL(tp_main<true>, dim3(192), dim3(256), 0, stream, XB1, XB2, Wtb, out);
    }
}